// Round 1
// baseline (1347.418 us; speedup 1.0000x reference)
//
#include <hip/hip_runtime.h>
#include <math.h>

#define DMODEL 1024
#define DINNER 2048
#define DCONV  4
#define DSTATE 16
#define DTRANK 64
#define BB 2
#define LL 1024
#define MM (BB * LL)            // 2048 rows in all GEMMs

// ---------------------------------------------------------------------------
// Generic f32 NT GEMM: C[m][n] = sum_k A[m][k] * Bw[n][k]  (+ optional epilogue)
// EPI 0: none; EPI 1: softplus(acc + bias[n])
// Requires: M % BM == 0, N % BN == 0, K % 16 == 0 (all true for our shapes).
// ---------------------------------------------------------------------------
template<int BM, int BN, int TM, int TN, int EPI>
__global__ __launch_bounds__(256)
void gemm_nt(const float* __restrict__ A, const float* __restrict__ Bw,
             float* __restrict__ C, const float* __restrict__ bias,
             int M, int N, int K, int lda, int ldb, int ldc) {
  constexpr int BK  = 16;
  constexpr int NTX = BN / TN;
  constexpr int NTY = BM / TM;
  static_assert(NTX * NTY == 256, "thread tile mismatch");
  __shared__ float As[BK][BM + 4];
  __shared__ float Bs[BK][BN + 4];

  const int tid = threadIdx.x;
  const int m0  = blockIdx.y * BM;
  const int n0  = blockIdx.x * BN;
  const int tx  = tid % NTX;
  const int ty  = tid / NTX;

  float acc[TM][TN] = {};

  for (int k0 = 0; k0 < K; k0 += BK) {
    __syncthreads();
    // stage A tile (BM x 16) transposed into As[k][m]
    for (int t = tid; t < BM * 4; t += 256) {
      const int row = t >> 2, kq = t & 3;
      const float4 v = *reinterpret_cast<const float4*>(
          A + (size_t)(m0 + row) * lda + k0 + kq * 4);
      As[kq * 4 + 0][row] = v.x;
      As[kq * 4 + 1][row] = v.y;
      As[kq * 4 + 2][row] = v.z;
      As[kq * 4 + 3][row] = v.w;
    }
    // stage B tile (BN x 16) transposed into Bs[k][n]
    for (int t = tid; t < BN * 4; t += 256) {
      const int row = t >> 2, kq = t & 3;
      const float4 v = *reinterpret_cast<const float4*>(
          Bw + (size_t)(n0 + row) * ldb + k0 + kq * 4);
      Bs[kq * 4 + 0][row] = v.x;
      Bs[kq * 4 + 1][row] = v.y;
      Bs[kq * 4 + 2][row] = v.z;
      Bs[kq * 4 + 3][row] = v.w;
    }
    __syncthreads();
    #pragma unroll
    for (int k = 0; k < BK; ++k) {
      float a[TM], b[TN];
      #pragma unroll
      for (int i = 0; i < TM; ++i) a[i] = As[k][ty * TM + i];
      #pragma unroll
      for (int j = 0; j < TN; ++j) b[j] = Bs[k][tx * TN + j];
      #pragma unroll
      for (int i = 0; i < TM; ++i)
        #pragma unroll
        for (int j = 0; j < TN; ++j)
          acc[i][j] = fmaf(a[i], b[j], acc[i][j]);
    }
  }

  #pragma unroll
  for (int i = 0; i < TM; ++i) {
    const int cm = m0 + ty * TM + i;
    #pragma unroll
    for (int j = 0; j < TN; ++j) {
      const int cn = n0 + tx * TN + j;
      float v = acc[i][j];
      if (EPI == 1) {
        v += bias[cn];
        v = (v > 20.f) ? v : log1pf(__expf(v));   // softplus
      }
      C[(size_t)cm * ldc + cn] = v;
    }
  }
}

// ---------------------------------------------------------------------------
// Depthwise causal conv1d (k=4) + bias + SiLU.  xi lives in xz[:, 0:2048].
// ---------------------------------------------------------------------------
__global__ __launch_bounds__(256)
void conv_silu(const float* __restrict__ xz, const float* __restrict__ cw,
               const float* __restrict__ cb, float* __restrict__ xc) {
  const int idx = blockIdx.x * 256 + threadIdx.x;
  if (idx >= MM * DINNER) return;
  const int d = idx & (DINNER - 1);
  const int m = idx >> 11;         // row in [0, 2048)
  const int l = m & (LL - 1);
  const int b = m >> 10;
  float acc = cb[d];
  #pragma unroll
  for (int j = 0; j < DCONV; ++j) {
    const int ll = l - (DCONV - 1) + j;
    if (ll >= 0)
      acc = fmaf(xz[((size_t)(b * LL + ll) << 12) + d], cw[d * DCONV + j], acc);
  }
  xc[idx] = acc / (1.f + __expf(-acc));   // silu
}

// ---------------------------------------------------------------------------
// Selective scan. One block = one b × 16 channels; lane = (channel, state n).
// Fused epilogue: y = (scan + xc*D) * silu(z)
// ---------------------------------------------------------------------------
__global__ __launch_bounds__(256)
void scan_kernel(const float* __restrict__ delta, const float* __restrict__ xc,
                 const float* __restrict__ xdbl, const float* __restrict__ xz,
                 const float* __restrict__ A_log, const float* __restrict__ Dp,
                 float* __restrict__ y) {
  const int b  = blockIdx.x >> 7;          // 128 d-groups per batch
  const int dg = blockIdx.x & 127;
  const int ty = threadIdx.x >> 4;         // 0..15  -> channel within group
  const int n  = threadIdx.x & 15;         // state index
  const int d  = dg * 16 + ty;

  const float Adn = -__expf(A_log[d * DSTATE + n]);
  const float Dd  = Dp[d];

  const float* __restrict__ dz  = delta + (size_t)b * LL * DINNER + d;
  const float* __restrict__ xcp = xc    + (size_t)b * LL * DINNER + d;
  const float* __restrict__ xd  = xdbl  + (size_t)b * LL * 96;
  const float* __restrict__ zp  = xz    + ((size_t)b * LL << 12) + DINNER + d;

  float h = 0.f;
  for (int l = 0; l < LL; ++l) {
    const float dv = dz[(size_t)l * DINNER];
    const float xv = xcp[(size_t)l * DINNER];
    const float Bv = xd[l * 96 + DTRANK + n];
    const float Cv = xd[l * 96 + DTRANK + DSTATE + n];

    const float a  = __expf(dv * Adn);
    const float bu = dv * Bv * xv;
    h = fmaf(a, h, bu);
    float yv = h * Cv;
    yv += __shfl_xor(yv, 1);
    yv += __shfl_xor(yv, 2);
    yv += __shfl_xor(yv, 4);
    yv += __shfl_xor(yv, 8);
    if (n == 0) {
      const float t  = yv + xv * Dd;
      const float zv = zp[(size_t)l << 12];
      const float g  = zv / (1.f + __expf(-zv));
      y[((size_t)(b * LL + l)) * DINNER + d] = t * g;
    }
  }
}

// ---------------------------------------------------------------------------
extern "C" void kernel_launch(void* const* d_in, const int* in_sizes, int n_in,
                              void* d_out, int out_size, void* d_ws, size_t ws_size,
                              hipStream_t stream) {
  const float* x         = (const float*)d_in[0];
  const float* in_proj_w = (const float*)d_in[1];
  const float* conv_w    = (const float*)d_in[2];
  const float* conv_b    = (const float*)d_in[3];
  const float* x_proj_w  = (const float*)d_in[4];
  const float* dt_proj_w = (const float*)d_in[5];
  const float* dt_proj_b = (const float*)d_in[6];
  const float* A_log     = (const float*)d_in[7];
  const float* Dv        = (const float*)d_in[8];
  const float* out_proj_w= (const float*)d_in[9];
  float* out = (float*)d_out;

  float* ws    = (float*)d_ws;
  float* xz    = ws;                         // [2048][4096]
  float* xc    = xz    + (size_t)MM * 4096;  // [2048][2048]
  float* xdbl  = xc    + (size_t)MM * DINNER;// [2048][96]
  float* delta = xdbl  + (size_t)MM * 96;    // [2048][2048]
  float* yb    = delta + (size_t)MM * DINNER;// [2048][2048]

  const dim3 blk(256);

  // 1) in_proj: xz = x @ in_proj_w^T   (M=2048, N=4096, K=1024)
  gemm_nt<128,128,8,8,0><<<dim3(4096/128, MM/128), blk, 0, stream>>>(
      x, in_proj_w, xz, nullptr, MM, 4096, DMODEL, DMODEL, DMODEL, 4096);

  // 2) causal depthwise conv + silu -> xc
  conv_silu<<<dim3((MM * DINNER) / 256), blk, 0, stream>>>(xz, conv_w, conv_b, xc);

  // 3) x_proj: xdbl = xc @ x_proj_w^T  (M=2048, N=96, K=2048)
  gemm_nt<64,32,4,2,0><<<dim3(96/32, MM/64), blk, 0, stream>>>(
      xc, x_proj_w, xdbl, nullptr, MM, 96, DINNER, DINNER, DINNER, 96);

  // 4) dt_proj + softplus: delta = softplus(xdbl[:, :64] @ dt_proj_w^T + b)
  gemm_nt<128,128,8,8,1><<<dim3(DINNER/128, MM/128), blk, 0, stream>>>(
      xdbl, dt_proj_w, delta, dt_proj_b, MM, DINNER, DTRANK, 96, DTRANK, DINNER);

  // 5) selective scan + gating epilogue -> yb
  scan_kernel<<<dim3(BB * (DINNER / 16)), blk, 0, stream>>>(
      delta, xc, xdbl, xz, A_log, Dv, yb);

  // 6) out_proj: out = yb @ out_proj_w^T (M=2048, N=1024, K=2048)
  gemm_nt<64,128,4,8,0><<<dim3(1024/128, MM/64), blk, 0, stream>>>(
      yb, out_proj_w, out, nullptr, MM, DMODEL, DINNER, DINNER, DINNER, DMODEL);
}

// Round 2
// 814.298 us; speedup vs baseline: 1.6547x; 1.6547x over previous
//
#include <hip/hip_runtime.h>
#include <math.h>
#include <stdint.h>

#define DMODEL 1024
#define DINNER 2048
#define DCONV  4
#define DSTATE 16
#define DTRANK 64
#define BB 2
#define LL 1024
#define MM (BB * LL)            // 2048 rows in all GEMMs

#define CL  64                  // scan chunk length
#define NCH (LL / CL)           // 16 chunks

// ---------------------------------------------------------------------------
// Generic f32 NT GEMM: C[m][n] = sum_k A[m][k] * Bw[n][k]  (+ optional epilogue)
// EPI 0: none; EPI 1: softplus(acc + bias[n])
// ---------------------------------------------------------------------------
template<int BM, int BN, int TM, int TN, int EPI>
__global__ __launch_bounds__(256)
void gemm_nt(const float* __restrict__ A, const float* __restrict__ Bw,
             float* __restrict__ C, const float* __restrict__ bias,
             int M, int N, int K, int lda, int ldb, int ldc) {
  constexpr int BK  = 16;
  constexpr int NTX = BN / TN;
  constexpr int NTY = BM / TM;
  static_assert(NTX * NTY == 256, "thread tile mismatch");
  __shared__ float As[BK][BM + 4];
  __shared__ float Bs[BK][BN + 4];

  const int tid = threadIdx.x;
  const int m0  = blockIdx.y * BM;
  const int n0  = blockIdx.x * BN;
  const int tx  = tid % NTX;
  const int ty  = tid / NTX;

  float acc[TM][TN] = {};

  for (int k0 = 0; k0 < K; k0 += BK) {
    __syncthreads();
    for (int t = tid; t < BM * 4; t += 256) {
      const int row = t >> 2, kq = t & 3;
      const float4 v = *reinterpret_cast<const float4*>(
          A + (size_t)(m0 + row) * lda + k0 + kq * 4);
      As[kq * 4 + 0][row] = v.x;
      As[kq * 4 + 1][row] = v.y;
      As[kq * 4 + 2][row] = v.z;
      As[kq * 4 + 3][row] = v.w;
    }
    for (int t = tid; t < BN * 4; t += 256) {
      const int row = t >> 2, kq = t & 3;
      const float4 v = *reinterpret_cast<const float4*>(
          Bw + (size_t)(n0 + row) * ldb + k0 + kq * 4);
      Bs[kq * 4 + 0][row] = v.x;
      Bs[kq * 4 + 1][row] = v.y;
      Bs[kq * 4 + 2][row] = v.z;
      Bs[kq * 4 + 3][row] = v.w;
    }
    __syncthreads();
    #pragma unroll
    for (int k = 0; k < BK; ++k) {
      float a[TM], b[TN];
      #pragma unroll
      for (int i = 0; i < TM; ++i) a[i] = As[k][ty * TM + i];
      #pragma unroll
      for (int j = 0; j < TN; ++j) b[j] = Bs[k][tx * TN + j];
      #pragma unroll
      for (int i = 0; i < TM; ++i)
        #pragma unroll
        for (int j = 0; j < TN; ++j)
          acc[i][j] = fmaf(a[i], b[j], acc[i][j]);
    }
  }

  #pragma unroll
  for (int i = 0; i < TM; ++i) {
    const int cm = m0 + ty * TM + i;
    #pragma unroll
    for (int j = 0; j < TN; ++j) {
      const int cn = n0 + tx * TN + j;
      float v = acc[i][j];
      if (EPI == 1) {
        v += bias[cn];
        v = (v > 20.f) ? v : log1pf(__expf(v));   // softplus
      }
      C[(size_t)cm * ldc + cn] = v;
    }
  }
}

// ---------------------------------------------------------------------------
// Depthwise causal conv1d (k=4) + bias + SiLU.  xi lives in xz[:, 0:2048].
// ---------------------------------------------------------------------------
__global__ __launch_bounds__(256)
void conv_silu(const float* __restrict__ xz, const float* __restrict__ cw,
               const float* __restrict__ cb, float* __restrict__ xc) {
  const int idx = blockIdx.x * 256 + threadIdx.x;
  if (idx >= MM * DINNER) return;
  const int d = idx & (DINNER - 1);
  const int m = idx >> 11;
  const int l = m & (LL - 1);
  const int b = m >> 10;
  float acc = cb[d];
  #pragma unroll
  for (int j = 0; j < DCONV; ++j) {
    const int ll = l - (DCONV - 1) + j;
    if (ll >= 0)
      acc = fmaf(xz[((size_t)(b * LL + ll) << 12) + d], cw[d * DCONV + j], acc);
  }
  xc[idx] = acc / (1.f + __expf(-acc));   // silu
}

// ---------------------------------------------------------------------------
// Selective scan, chunked-LDS version.
// Grid: 256 blocks = (b, dg) with 16 channels per block. Block = 64 threads
// (1 wave): thread t -> channel ch = t>>2, states 4q..4q+3 with q = t&3.
// Chunks of CL=64 steps staged into double-buffered LDS via global_load_lds.
// ---------------------------------------------------------------------------
#define AS1(p) ((__attribute__((address_space(1))) void*)(void*)(p))
#define AS3(p) ((__attribute__((address_space(3))) void*)(void*)(p))

// stage a [CL=64][16]-float tile: 4 wave-wide dwordx4 direct-to-LDS loads
__device__ __forceinline__ void stage_tile(const float* g, int stride,
                                           float* ldst, int lane) {
  const int r  = lane >> 2;
  const int q4 = (lane & 3) * 4;
  #pragma unroll
  for (int i = 0; i < 4; ++i) {
    __builtin_amdgcn_global_load_lds(
        AS1(g + (size_t)(i * 16 + r) * stride + q4),
        AS3(ldst + i * 256), 16, 0, 0);
  }
}

__device__ __forceinline__ float quad_sum(float v) {
  // sum over lanes within each quad via DPP quad_perm (VALU pipe, not LDS)
  int i = __float_as_int(v);
  v += __int_as_float(__builtin_amdgcn_update_dpp(0, i, 0xB1, 0xf, 0xf, true)); // xor 1
  i = __float_as_int(v);
  v += __int_as_float(__builtin_amdgcn_update_dpp(0, i, 0x4E, 0xf, 0xf, true)); // xor 2
  return v;
}

__global__ __launch_bounds__(64)
void scan_kernel(const float* __restrict__ delta, const float* __restrict__ xc,
                 const float* __restrict__ xdbl, const float* __restrict__ xz,
                 const float* __restrict__ A_log, const float* __restrict__ Dp,
                 float* __restrict__ y) {
  __shared__ float dT[2][CL][16];
  __shared__ float xT[2][CL][16];
  __shared__ float bT[2][CL][16];
  __shared__ float cT[2][CL][16];
  __shared__ float zT[2][CL][16];

  const int b  = blockIdx.x >> 7;
  const int dg = blockIdx.x & 127;
  const int t  = threadIdx.x;        // 0..63
  const int ch = t >> 2;
  const int q  = t & 3;
  const int d  = dg * 16 + ch;

  float Adn[4];
  #pragma unroll
  for (int j = 0; j < 4; ++j)
    Adn[j] = -__expf(A_log[d * DSTATE + 4 * q + j]);
  const float Dd = Dp[d];
  float h0 = 0.f, h1 = 0.f, h2 = 0.f, h3 = 0.f;

  const size_t rowb = (size_t)b * LL;

  // stage chunk 0 into buffer 0
  {
    const size_t r0 = rowb;
    stage_tile(delta + r0 * DINNER + dg * 16, DINNER, &dT[0][0][0], t);
    stage_tile(xc    + r0 * DINNER + dg * 16, DINNER, &xT[0][0][0], t);
    stage_tile(xdbl  + r0 * 96 + DTRANK,          96, &bT[0][0][0], t);
    stage_tile(xdbl  + r0 * 96 + DTRANK + DSTATE, 96, &cT[0][0][0], t);
    stage_tile(xz    + (r0 << 12) + DINNER + dg * 16, 4096, &zT[0][0][0], t);
  }
  __syncthreads();

  for (int c = 0; c < NCH; ++c) {
    const int buf = c & 1;
    if (c + 1 < NCH) {
      const int nb = buf ^ 1;
      const size_t r0 = rowb + (size_t)(c + 1) * CL;
      stage_tile(delta + r0 * DINNER + dg * 16, DINNER, &dT[nb][0][0], t);
      stage_tile(xc    + r0 * DINNER + dg * 16, DINNER, &xT[nb][0][0], t);
      stage_tile(xdbl  + r0 * 96 + DTRANK,          96, &bT[nb][0][0], t);
      stage_tile(xdbl  + r0 * 96 + DTRANK + DSTATE, 96, &cT[nb][0][0], t);
      stage_tile(xz    + (r0 << 12) + DINNER + dg * 16, 4096, &zT[nb][0][0], t);
    }
    const int lbase = c * CL;
    #pragma unroll 8
    for (int l = 0; l < CL; ++l) {
      const float dv = dT[buf][l][ch];
      const float xv = xT[buf][l][ch];
      const float4 B4 = *reinterpret_cast<const float4*>(&bT[buf][l][4 * q]);
      const float4 C4 = *reinterpret_cast<const float4*>(&cT[buf][l][4 * q]);
      const float dvx = dv * xv;
      const float a0 = __expf(dv * Adn[0]);
      const float a1 = __expf(dv * Adn[1]);
      const float a2 = __expf(dv * Adn[2]);
      const float a3 = __expf(dv * Adn[3]);
      h0 = fmaf(a0, h0, dvx * B4.x);
      h1 = fmaf(a1, h1, dvx * B4.y);
      h2 = fmaf(a2, h2, dvx * B4.z);
      h3 = fmaf(a3, h3, dvx * B4.w);
      float ys = fmaf(h0, C4.x, fmaf(h1, C4.y, fmaf(h2, C4.z, h3 * C4.w)));
      ys = quad_sum(ys);
      if (q == 0) {
        const float zv = zT[buf][l][ch];
        const float g  = zv / (1.f + __expf(-zv));
        y[(rowb + lbase + l) * (size_t)DINNER + d] = (ys + xv * Dd) * g;
      }
    }
    __syncthreads();   // drains vmcnt: next buffer's loads have landed
  }
}

// ---------------------------------------------------------------------------
extern "C" void kernel_launch(void* const* d_in, const int* in_sizes, int n_in,
                              void* d_out, int out_size, void* d_ws, size_t ws_size,
                              hipStream_t stream) {
  const float* x         = (const float*)d_in[0];
  const float* in_proj_w = (const float*)d_in[1];
  const float* conv_w    = (const float*)d_in[2];
  const float* conv_b    = (const float*)d_in[3];
  const float* x_proj_w  = (const float*)d_in[4];
  const float* dt_proj_w = (const float*)d_in[5];
  const float* dt_proj_b = (const float*)d_in[6];
  const float* A_log     = (const float*)d_in[7];
  const float* Dv        = (const float*)d_in[8];
  const float* out_proj_w= (const float*)d_in[9];
  float* out = (float*)d_out;

  float* ws    = (float*)d_ws;
  float* xz    = ws;                         // [2048][4096]
  float* xc    = xz    + (size_t)MM * 4096;  // [2048][2048]
  float* xdbl  = xc    + (size_t)MM * DINNER;// [2048][96]
  float* delta = xdbl  + (size_t)MM * 96;    // [2048][2048]
  float* yb    = delta + (size_t)MM * DINNER;// [2048][2048]

  const dim3 blk(256);

  // 1) in_proj: xz = x @ in_proj_w^T   (M=2048, N=4096, K=1024)
  gemm_nt<128,128,8,8,0><<<dim3(4096/128, MM/128), blk, 0, stream>>>(
      x, in_proj_w, xz, nullptr, MM, 4096, DMODEL, DMODEL, DMODEL, 4096);

  // 2) causal depthwise conv + silu -> xc
  conv_silu<<<dim3((MM * DINNER) / 256), blk, 0, stream>>>(xz, conv_w, conv_b, xc);

  // 3) x_proj: xdbl = xc @ x_proj_w^T  (M=2048, N=96, K=2048)
  gemm_nt<64,32,4,2,0><<<dim3(96/32, MM/64), blk, 0, stream>>>(
      xc, x_proj_w, xdbl, nullptr, MM, 96, DINNER, DINNER, DINNER, 96);

  // 4) dt_proj + softplus: delta = softplus(xdbl[:, :64] @ dt_proj_w^T + b)
  gemm_nt<128,128,8,8,1><<<dim3(DINNER/128, MM/128), blk, 0, stream>>>(
      xdbl, dt_proj_w, delta, dt_proj_b, MM, DINNER, DTRANK, 96, DTRANK, DINNER);

  // 5) selective scan + gating epilogue -> yb  (64-thread blocks!)
  scan_kernel<<<dim3(BB * (DINNER / 16)), dim3(64), 0, stream>>>(
      delta, xc, xdbl, xz, A_log, Dv, yb);

  // 6) out_proj: out = yb @ out_proj_w^T (M=2048, N=1024, K=2048)
  gemm_nt<64,128,4,8,0><<<dim3(1024/128, MM/64), blk, 0, stream>>>(
      yb, out_proj_w, out, nullptr, MM, DMODEL, DINNER, DINNER, DINNER, DMODEL);
}

// Round 3
// 518.639 us; speedup vs baseline: 2.5980x; 1.5701x over previous
//
#include <hip/hip_runtime.h>
#include <math.h>
#include <stdint.h>

#define DMODEL 1024
#define DINNER 2048
#define DCONV  4
#define DSTATE 16
#define DTRANK 64
#define BB 2
#define LL 1024
#define MM (BB * LL)            // 2048 rows in all GEMMs

#define CL  64                  // scan chunk length
#define NCH (LL / CL)           // 16 chunks

#define AS1(p) ((__attribute__((address_space(1))) void*)(void*)(p))
#define AS3(p) ((__attribute__((address_space(3))) void*)(void*)(p))

typedef __attribute__((ext_vector_type(8))) short bf16x8;
typedef __attribute__((ext_vector_type(4))) float f32x4;

__device__ __forceinline__ ushort bf16_rne(float f) {
  uint32_t u = __float_as_uint(f);
  uint32_t r = (u + 0x7fffu + ((u >> 16) & 1u)) >> 16;
  return (ushort)r;
}

// ---------------------------------------------------------------------------
// f32 -> (hi, lo) bf16 planes.  n % 4 == 0.
// ---------------------------------------------------------------------------
__global__ __launch_bounds__(256)
void split_hl(const float* __restrict__ in, ushort* __restrict__ hi,
              ushort* __restrict__ lo, int n) {
  const int i = (blockIdx.x * 256 + threadIdx.x) * 4;
  if (i >= n) return;
  const float4 v = *reinterpret_cast<const float4*>(in + i);
  ushort4 h, l;
  h.x = bf16_rne(v.x); l.x = bf16_rne(v.x - __uint_as_float((uint)h.x << 16));
  h.y = bf16_rne(v.y); l.y = bf16_rne(v.y - __uint_as_float((uint)h.y << 16));
  h.z = bf16_rne(v.z); l.z = bf16_rne(v.z - __uint_as_float((uint)h.z << 16));
  h.w = bf16_rne(v.w); l.w = bf16_rne(v.w - __uint_as_float((uint)h.w << 16));
  *reinterpret_cast<ushort4*>(hi + i) = h;
  *reinterpret_cast<ushort4*>(lo + i) = l;
}

// ---------------------------------------------------------------------------
// Split-precision bf16 MFMA NT GEMM: C = A @ B^T, A[M][K], B[N][K] (hi/lo planes).
// 128x128 tile, BK=32, 4 waves (2x2 of 64x64), global_load_lds staging,
// XOR-swizzled LDS (slot ^= (r&3)^((r>>2)&3)) -> 2-way conflicts (free).
// ---------------------------------------------------------------------------
__device__ __forceinline__ int swz4(int r) { return (r & 3) ^ ((r >> 2) & 3); }

__global__ __launch_bounds__(256)
void gemm_hl_mfma(const ushort* __restrict__ Ahg, const ushort* __restrict__ Alg,
                  const ushort* __restrict__ Bhg, const ushort* __restrict__ Blg,
                  float* __restrict__ C, int M, int N, int K) {
  __shared__ ushort Ah[128][32];
  __shared__ ushort Al[128][32];
  __shared__ ushort Bh[128][32];
  __shared__ ushort Bl[128][32];

  const int tid  = threadIdx.x;
  const int wave = tid >> 6;
  const int lane = tid & 63;
  const int m0 = blockIdx.y * 128;
  const int n0 = blockIdx.x * 128;
  const int wm = (wave >> 1) * 64;
  const int wn = (wave & 1) * 64;

  f32x4 acc[4][4];
  #pragma unroll
  for (int i = 0; i < 4; ++i)
    #pragma unroll
    for (int j = 0; j < 4; ++j)
      acc[i][j] = (f32x4){0.f, 0.f, 0.f, 0.f};

  // per-wave staging assignment
  const ushort* gsrc; ushort* dst; int row0;
  if      (wave == 0) { gsrc = Ahg; dst = &Ah[0][0]; row0 = m0; }
  else if (wave == 1) { gsrc = Alg; dst = &Al[0][0]; row0 = m0; }
  else if (wave == 2) { gsrc = Bhg; dst = &Bh[0][0]; row0 = n0; }
  else                { gsrc = Blg; dst = &Bl[0][0]; row0 = n0; }

  const int lr = lane >> 2;   // row within 16-row segment
  const int ls = lane & 3;    // 16B slot within 64B row

  const int fr = lane & 15;
  const int q  = lane >> 4;

  for (int k0 = 0; k0 < K; k0 += 32) {
    if (k0) __syncthreads();
    #pragma unroll
    for (int seg = 0; seg < 8; ++seg) {
      const int rho = seg * 16 + lr;
      const int ks  = (ls ^ swz4(rho)) * 8;   // pre-swizzled global source
      __builtin_amdgcn_global_load_lds(
          AS1(gsrc + (size_t)(row0 + rho) * K + k0 + ks),
          AS3(dst + seg * 512), 16, 0, 0);
    }
    __syncthreads();   // drains vmcnt -> tiles resident

    bf16x8 ah[4], al[4], bh[4], bl[4];
    #pragma unroll
    for (int f = 0; f < 4; ++f) {
      { const int r = wm + f * 16 + fr; const int s = 8 * (q ^ swz4(r));
        ah[f] = *reinterpret_cast<const bf16x8*>(&Ah[r][s]);
        al[f] = *reinterpret_cast<const bf16x8*>(&Al[r][s]); }
      { const int r = wn + f * 16 + fr; const int s = 8 * (q ^ swz4(r));
        bh[f] = *reinterpret_cast<const bf16x8*>(&Bh[r][s]);
        bl[f] = *reinterpret_cast<const bf16x8*>(&Bl[r][s]); }
    }
    #pragma unroll
    for (int i = 0; i < 4; ++i)
      #pragma unroll
      for (int j = 0; j < 4; ++j) {
        acc[i][j] = __builtin_amdgcn_mfma_f32_16x16x32_bf16(ah[i], bh[j], acc[i][j], 0, 0, 0);
        acc[i][j] = __builtin_amdgcn_mfma_f32_16x16x32_bf16(al[i], bh[j], acc[i][j], 0, 0, 0);
        acc[i][j] = __builtin_amdgcn_mfma_f32_16x16x32_bf16(ah[i], bl[j], acc[i][j], 0, 0, 0);
      }
  }

  // epilogue: C/D layout col = lane&15, row = (lane>>4)*4 + reg
  const int cr = (lane >> 4) * 4;
  const int cc = lane & 15;
  #pragma unroll
  for (int i = 0; i < 4; ++i)
    #pragma unroll
    for (int j = 0; j < 4; ++j) {
      const size_t base = (size_t)(m0 + wm + i * 16 + cr) * N + (n0 + wn + j * 16 + cc);
      #pragma unroll
      for (int r = 0; r < 4; ++r)
        C[base + (size_t)r * N] = acc[i][j][r];
    }
}

// ---------------------------------------------------------------------------
// Generic f32 NT GEMM (kept for x_proj / dt_proj).
// ---------------------------------------------------------------------------
template<int BM, int BN, int TM, int TN, int EPI>
__global__ __launch_bounds__(256)
void gemm_nt(const float* __restrict__ A, const float* __restrict__ Bw,
             float* __restrict__ C, const float* __restrict__ bias,
             int M, int N, int K, int lda, int ldb, int ldc) {
  constexpr int BK  = 16;
  constexpr int NTX = BN / TN;
  constexpr int NTY = BM / TM;
  static_assert(NTX * NTY == 256, "thread tile mismatch");
  __shared__ float As[BK][BM + 4];
  __shared__ float Bs[BK][BN + 4];

  const int tid = threadIdx.x;
  const int m0  = blockIdx.y * BM;
  const int n0  = blockIdx.x * BN;
  const int tx  = tid % NTX;
  const int ty  = tid / NTX;

  float acc[TM][TN] = {};

  for (int k0 = 0; k0 < K; k0 += BK) {
    __syncthreads();
    for (int t = tid; t < BM * 4; t += 256) {
      const int row = t >> 2, kq = t & 3;
      const float4 v = *reinterpret_cast<const float4*>(
          A + (size_t)(m0 + row) * lda + k0 + kq * 4);
      As[kq * 4 + 0][row] = v.x;
      As[kq * 4 + 1][row] = v.y;
      As[kq * 4 + 2][row] = v.z;
      As[kq * 4 + 3][row] = v.w;
    }
    for (int t = tid; t < BN * 4; t += 256) {
      const int row = t >> 2, kq = t & 3;
      const float4 v = *reinterpret_cast<const float4*>(
          Bw + (size_t)(n0 + row) * ldb + k0 + kq * 4);
      Bs[kq * 4 + 0][row] = v.x;
      Bs[kq * 4 + 1][row] = v.y;
      Bs[kq * 4 + 2][row] = v.z;
      Bs[kq * 4 + 3][row] = v.w;
    }
    __syncthreads();
    #pragma unroll
    for (int k = 0; k < BK; ++k) {
      float a[TM], b[TN];
      #pragma unroll
      for (int i = 0; i < TM; ++i) a[i] = As[k][ty * TM + i];
      #pragma unroll
      for (int j = 0; j < TN; ++j) b[j] = Bs[k][tx * TN + j];
      #pragma unroll
      for (int i = 0; i < TM; ++i)
        #pragma unroll
        for (int j = 0; j < TN; ++j)
          acc[i][j] = fmaf(a[i], b[j], acc[i][j]);
    }
  }

  #pragma unroll
  for (int i = 0; i < TM; ++i) {
    const int cm = m0 + ty * TM + i;
    #pragma unroll
    for (int j = 0; j < TN; ++j) {
      const int cn = n0 + tx * TN + j;
      float v = acc[i][j];
      if (EPI == 1) {
        v += bias[cn];
        v = (v > 20.f) ? v : log1pf(__expf(v));   // softplus
      }
      C[(size_t)cm * ldc + cn] = v;
    }
  }
}

// ---------------------------------------------------------------------------
// Depthwise causal conv1d (k=4) + bias + SiLU.
// ---------------------------------------------------------------------------
__global__ __launch_bounds__(256)
void conv_silu(const float* __restrict__ xz, const float* __restrict__ cw,
               const float* __restrict__ cb, float* __restrict__ xc) {
  const int idx = blockIdx.x * 256 + threadIdx.x;
  if (idx >= MM * DINNER) return;
  const int d = idx & (DINNER - 1);
  const int m = idx >> 11;
  const int l = m & (LL - 1);
  const int b = m >> 10;
  float acc = cb[d];
  #pragma unroll
  for (int j = 0; j < DCONV; ++j) {
    const int ll = l - (DCONV - 1) + j;
    if (ll >= 0)
      acc = fmaf(xz[((size_t)(b * LL + ll) << 12) + d], cw[d * DCONV + j], acc);
  }
  xc[idx] = acc / (1.f + __expf(-acc));   // silu
}

// ---------------------------------------------------------------------------
// Selective scan, chunked-LDS, 64-thread blocks. Outputs y as bf16 hi/lo.
// ---------------------------------------------------------------------------
__device__ __forceinline__ void stage_tile(const float* g, int stride,
                                           float* ldst, int lane) {
  const int r  = lane >> 2;
  const int q4 = (lane & 3) * 4;
  #pragma unroll
  for (int i = 0; i < 4; ++i) {
    __builtin_amdgcn_global_load_lds(
        AS1(g + (size_t)(i * 16 + r) * stride + q4),
        AS3(ldst + i * 256), 16, 0, 0);
  }
}

__device__ __forceinline__ float quad_sum(float v) {
  int i = __float_as_int(v);
  v += __int_as_float(__builtin_amdgcn_update_dpp(0, i, 0xB1, 0xf, 0xf, true)); // xor 1
  i = __float_as_int(v);
  v += __int_as_float(__builtin_amdgcn_update_dpp(0, i, 0x4E, 0xf, 0xf, true)); // xor 2
  return v;
}

__global__ __launch_bounds__(64)
void scan_kernel(const float* __restrict__ delta, const float* __restrict__ xc,
                 const float* __restrict__ xdbl, const float* __restrict__ xz,
                 const float* __restrict__ A_log, const float* __restrict__ Dp,
                 ushort* __restrict__ yh, ushort* __restrict__ yl) {
  __shared__ float dT[2][CL][16];
  __shared__ float xT[2][CL][16];
  __shared__ float bT[2][CL][16];
  __shared__ float cT[2][CL][16];
  __shared__ float zT[2][CL][16];

  const int b  = blockIdx.x >> 7;
  const int dg = blockIdx.x & 127;
  const int t  = threadIdx.x;        // 0..63
  const int ch = t >> 2;
  const int q  = t & 3;
  const int d  = dg * 16 + ch;

  float Adn[4];
  #pragma unroll
  for (int j = 0; j < 4; ++j)
    Adn[j] = -__expf(A_log[d * DSTATE + 4 * q + j]);
  const float Dd = Dp[d];
  float h0 = 0.f, h1 = 0.f, h2 = 0.f, h3 = 0.f;

  const size_t rowb = (size_t)b * LL;

  {
    const size_t r0 = rowb;
    stage_tile(delta + r0 * DINNER + dg * 16, DINNER, &dT[0][0][0], t);
    stage_tile(xc    + r0 * DINNER + dg * 16, DINNER, &xT[0][0][0], t);
    stage_tile(xdbl  + r0 * 96 + DTRANK,          96, &bT[0][0][0], t);
    stage_tile(xdbl  + r0 * 96 + DTRANK + DSTATE, 96, &cT[0][0][0], t);
    stage_tile(xz    + (r0 << 12) + DINNER + dg * 16, 4096, &zT[0][0][0], t);
  }
  __syncthreads();

  for (int c = 0; c < NCH; ++c) {
    const int buf = c & 1;
    if (c + 1 < NCH) {
      const int nb = buf ^ 1;
      const size_t r0 = rowb + (size_t)(c + 1) * CL;
      stage_tile(delta + r0 * DINNER + dg * 16, DINNER, &dT[nb][0][0], t);
      stage_tile(xc    + r0 * DINNER + dg * 16, DINNER, &xT[nb][0][0], t);
      stage_tile(xdbl  + r0 * 96 + DTRANK,          96, &bT[nb][0][0], t);
      stage_tile(xdbl  + r0 * 96 + DTRANK + DSTATE, 96, &cT[nb][0][0], t);
      stage_tile(xz    + (r0 << 12) + DINNER + dg * 16, 4096, &zT[nb][0][0], t);
    }
    const int lbase = c * CL;
    #pragma unroll 8
    for (int l = 0; l < CL; ++l) {
      const float dv = dT[buf][l][ch];
      const float xv = xT[buf][l][ch];
      const float4 B4 = *reinterpret_cast<const float4*>(&bT[buf][l][4 * q]);
      const float4 C4 = *reinterpret_cast<const float4*>(&cT[buf][l][4 * q]);
      const float dvx = dv * xv;
      const float a0 = __expf(dv * Adn[0]);
      const float a1 = __expf(dv * Adn[1]);
      const float a2 = __expf(dv * Adn[2]);
      const float a3 = __expf(dv * Adn[3]);
      h0 = fmaf(a0, h0, dvx * B4.x);
      h1 = fmaf(a1, h1, dvx * B4.y);
      h2 = fmaf(a2, h2, dvx * B4.z);
      h3 = fmaf(a3, h3, dvx * B4.w);
      float ys = fmaf(h0, C4.x, fmaf(h1, C4.y, fmaf(h2, C4.z, h3 * C4.w)));
      ys = quad_sum(ys);
      if (q == 0) {
        const float zv = zT[buf][l][ch];
        const float g  = zv / (1.f + __expf(-zv));
        const float tv = (ys + xv * Dd) * g;
        const size_t idx = (rowb + lbase + l) * (size_t)DINNER + d;
        const ushort hh = bf16_rne(tv);
        yh[idx] = hh;
        yl[idx] = bf16_rne(tv - __uint_as_float((uint)hh << 16));
      }
    }
    __syncthreads();
  }
}

// ---------------------------------------------------------------------------
extern "C" void kernel_launch(void* const* d_in, const int* in_sizes, int n_in,
                              void* d_out, int out_size, void* d_ws, size_t ws_size,
                              hipStream_t stream) {
  const float* x         = (const float*)d_in[0];
  const float* in_proj_w = (const float*)d_in[1];
  const float* conv_w    = (const float*)d_in[2];
  const float* conv_b    = (const float*)d_in[3];
  const float* x_proj_w  = (const float*)d_in[4];
  const float* dt_proj_w = (const float*)d_in[5];
  const float* dt_proj_b = (const float*)d_in[6];
  const float* A_log     = (const float*)d_in[7];
  const float* Dv        = (const float*)d_in[8];
  const float* out_proj_w= (const float*)d_in[9];
  float* out = (float*)d_out;

  float* ws    = (float*)d_ws;
  float* xz    = ws;                          // [2048][4096] f32
  float* xc    = xz    + (size_t)MM * 4096;   // [2048][2048] f32
  float* xdbl  = xc    + (size_t)MM * DINNER; // [2048][96]   f32
  float* delta = xdbl  + (size_t)MM * 96;     // [2048][2048] f32
  ushort* us   = (ushort*)(delta + (size_t)MM * DINNER);
  ushort* yhp  = us;                           // [2048][2048] bf16 hi
  ushort* ylp  = yhp + (size_t)MM * DINNER;    // [2048][2048] bf16 lo
  ushort* xh   = ylp + (size_t)MM * DINNER;    // [2048][1024]
  ushort* xl   = xh  + (size_t)MM * DMODEL;
  ushort* wih  = xl  + (size_t)MM * DMODEL;    // [4096][1024]
  ushort* wil  = wih + (size_t)4096 * DMODEL;
  ushort* woh  = wil + (size_t)4096 * DMODEL;  // [1024][2048]
  ushort* wol  = woh + (size_t)DMODEL * DINNER;

  const dim3 blk(256);

  // 0) precision splits
  split_hl<<<dim3((MM * DMODEL) / 1024), blk, 0, stream>>>(x, xh, xl, MM * DMODEL);
  split_hl<<<dim3((4096 * DMODEL) / 1024), blk, 0, stream>>>(in_proj_w, wih, wil, 4096 * DMODEL);
  split_hl<<<dim3((DMODEL * DINNER) / 1024), blk, 0, stream>>>(out_proj_w, woh, wol, DMODEL * DINNER);

  // 1) in_proj (MFMA split-bf16): xz = x @ in_proj_w^T  (M=2048,N=4096,K=1024)
  gemm_hl_mfma<<<dim3(4096 / 128, MM / 128), blk, 0, stream>>>(
      xh, xl, wih, wil, xz, MM, 4096, DMODEL);

  // 2) causal depthwise conv + silu -> xc
  conv_silu<<<dim3((MM * DINNER) / 256), blk, 0, stream>>>(xz, conv_w, conv_b, xc);

  // 3) x_proj: xdbl = xc @ x_proj_w^T  (M=2048, N=96, K=2048)
  gemm_nt<64,32,4,2,0><<<dim3(96/32, MM/64), blk, 0, stream>>>(
      xc, x_proj_w, xdbl, nullptr, MM, 96, DINNER, DINNER, DINNER, 96);

  // 4) dt_proj + softplus
  gemm_nt<128,128,8,8,1><<<dim3(DINNER/128, MM/128), blk, 0, stream>>>(
      xdbl, dt_proj_w, delta, dt_proj_b, MM, DINNER, DTRANK, 96, DTRANK, DINNER);

  // 5) selective scan + gating -> y (bf16 hi/lo planes)
  scan_kernel<<<dim3(BB * (DINNER / 16)), dim3(64), 0, stream>>>(
      delta, xc, xdbl, xz, A_log, Dv, yhp, ylp);

  // 6) out_proj (MFMA split-bf16): out = y @ out_proj_w^T (M=2048,N=1024,K=2048)
  gemm_hl_mfma<<<dim3(DMODEL / 128, MM / 128), blk, 0, stream>>>(
      yhp, ylp, woh, wol, out, MM, DMODEL, DINNER);
}

// Round 4
// 392.349 us; speedup vs baseline: 3.4342x; 1.3219x over previous
//
#include <hip/hip_runtime.h>
#include <math.h>
#include <stdint.h>

#define DMODEL 1024
#define DINNER 2048
#define DCONV  4
#define DSTATE 16
#define DTRANK 64
#define BB 2
#define LL 1024
#define MM (BB * LL)            // 2048 rows in all GEMMs

#define CL  64                  // scan chunk length
#define NCH (LL / CL)           // 16 chunks

#define AS1(p) ((__attribute__((address_space(1))) void*)(void*)(p))
#define AS3(p) ((__attribute__((address_space(3))) void*)(void*)(p))

typedef __attribute__((ext_vector_type(8))) short bf16x8;
typedef __attribute__((ext_vector_type(4))) float f32x4;

__device__ __forceinline__ ushort bf16_rne(float f) {
  uint32_t u = __float_as_uint(f);
  uint32_t r = (u + 0x7fffu + ((u >> 16) & 1u)) >> 16;
  return (ushort)r;
}

// ---------------------------------------------------------------------------
// f32 -> (hi, lo) bf16 planes.  n % 4 == 0.
// ---------------------------------------------------------------------------
__global__ __launch_bounds__(256)
void split_hl(const float* __restrict__ in, ushort* __restrict__ hi,
              ushort* __restrict__ lo, int n) {
  const int i = (blockIdx.x * 256 + threadIdx.x) * 4;
  if (i >= n) return;
  const float4 v = *reinterpret_cast<const float4*>(in + i);
  ushort4 h, l;
  h.x = bf16_rne(v.x); l.x = bf16_rne(v.x - __uint_as_float((uint)h.x << 16));
  h.y = bf16_rne(v.y); l.y = bf16_rne(v.y - __uint_as_float((uint)h.y << 16));
  h.z = bf16_rne(v.z); l.z = bf16_rne(v.z - __uint_as_float((uint)h.z << 16));
  h.w = bf16_rne(v.w); l.w = bf16_rne(v.w - __uint_as_float((uint)h.w << 16));
  *reinterpret_cast<ushort4*>(hi + i) = h;
  *reinterpret_cast<ushort4*>(lo + i) = l;
}

// ---------------------------------------------------------------------------
// Split-precision bf16 MFMA NT GEMM (unchanged from round 3).
// ---------------------------------------------------------------------------
__device__ __forceinline__ int swz4(int r) { return (r & 3) ^ ((r >> 2) & 3); }

__global__ __launch_bounds__(256)
void gemm_hl_mfma(const ushort* __restrict__ Ahg, const ushort* __restrict__ Alg,
                  const ushort* __restrict__ Bhg, const ushort* __restrict__ Blg,
                  float* __restrict__ C, int M, int N, int K) {
  __shared__ ushort Ah[128][32];
  __shared__ ushort Al[128][32];
  __shared__ ushort Bh[128][32];
  __shared__ ushort Bl[128][32];

  const int tid  = threadIdx.x;
  const int wave = tid >> 6;
  const int lane = tid & 63;
  const int m0 = blockIdx.y * 128;
  const int n0 = blockIdx.x * 128;
  const int wm = (wave >> 1) * 64;
  const int wn = (wave & 1) * 64;

  f32x4 acc[4][4];
  #pragma unroll
  for (int i = 0; i < 4; ++i)
    #pragma unroll
    for (int j = 0; j < 4; ++j)
      acc[i][j] = (f32x4){0.f, 0.f, 0.f, 0.f};

  const ushort* gsrc; ushort* dst; int row0;
  if      (wave == 0) { gsrc = Ahg; dst = &Ah[0][0]; row0 = m0; }
  else if (wave == 1) { gsrc = Alg; dst = &Al[0][0]; row0 = m0; }
  else if (wave == 2) { gsrc = Bhg; dst = &Bh[0][0]; row0 = n0; }
  else                { gsrc = Blg; dst = &Bl[0][0]; row0 = n0; }

  const int lr = lane >> 2;
  const int ls = lane & 3;
  const int fr = lane & 15;
  const int q  = lane >> 4;

  for (int k0 = 0; k0 < K; k0 += 32) {
    if (k0) __syncthreads();
    #pragma unroll
    for (int seg = 0; seg < 8; ++seg) {
      const int rho = seg * 16 + lr;
      const int ks  = (ls ^ swz4(rho)) * 8;
      __builtin_amdgcn_global_load_lds(
          AS1(gsrc + (size_t)(row0 + rho) * K + k0 + ks),
          AS3(dst + seg * 512), 16, 0, 0);
    }
    __syncthreads();

    bf16x8 ah[4], al[4], bh[4], bl[4];
    #pragma unroll
    for (int f = 0; f < 4; ++f) {
      { const int r = wm + f * 16 + fr; const int s = 8 * (q ^ swz4(r));
        ah[f] = *reinterpret_cast<const bf16x8*>(&Ah[r][s]);
        al[f] = *reinterpret_cast<const bf16x8*>(&Al[r][s]); }
      { const int r = wn + f * 16 + fr; const int s = 8 * (q ^ swz4(r));
        bh[f] = *reinterpret_cast<const bf16x8*>(&Bh[r][s]);
        bl[f] = *reinterpret_cast<const bf16x8*>(&Bl[r][s]); }
    }
    #pragma unroll
    for (int i = 0; i < 4; ++i)
      #pragma unroll
      for (int j = 0; j < 4; ++j) {
        acc[i][j] = __builtin_amdgcn_mfma_f32_16x16x32_bf16(ah[i], bh[j], acc[i][j], 0, 0, 0);
        acc[i][j] = __builtin_amdgcn_mfma_f32_16x16x32_bf16(al[i], bh[j], acc[i][j], 0, 0, 0);
        acc[i][j] = __builtin_amdgcn_mfma_f32_16x16x32_bf16(ah[i], bl[j], acc[i][j], 0, 0, 0);
      }
  }

  const int cr = (lane >> 4) * 4;
  const int cc = lane & 15;
  #pragma unroll
  for (int i = 0; i < 4; ++i)
    #pragma unroll
    for (int j = 0; j < 4; ++j) {
      const size_t base = (size_t)(m0 + wm + i * 16 + cr) * N + (n0 + wn + j * 16 + cc);
      #pragma unroll
      for (int r = 0; r < 4; ++r)
        C[base + (size_t)r * N] = acc[i][j][r];
    }
}

// ---------------------------------------------------------------------------
// Generic f32 NT GEMM (x_proj / dt_proj).
// ---------------------------------------------------------------------------
template<int BM, int BN, int TM, int TN, int EPI>
__global__ __launch_bounds__(256)
void gemm_nt(const float* __restrict__ A, const float* __restrict__ Bw,
             float* __restrict__ C, const float* __restrict__ bias,
             int M, int N, int K, int lda, int ldb, int ldc) {
  constexpr int BK  = 16;
  constexpr int NTX = BN / TN;
  constexpr int NTY = BM / TM;
  static_assert(NTX * NTY == 256, "thread tile mismatch");
  __shared__ float As[BK][BM + 4];
  __shared__ float Bs[BK][BN + 4];

  const int tid = threadIdx.x;
  const int m0  = blockIdx.y * BM;
  const int n0  = blockIdx.x * BN;
  const int tx  = tid % NTX;
  const int ty  = tid / NTX;

  float acc[TM][TN] = {};

  for (int k0 = 0; k0 < K; k0 += BK) {
    __syncthreads();
    for (int t = tid; t < BM * 4; t += 256) {
      const int row = t >> 2, kq = t & 3;
      const float4 v = *reinterpret_cast<const float4*>(
          A + (size_t)(m0 + row) * lda + k0 + kq * 4);
      As[kq * 4 + 0][row] = v.x;
      As[kq * 4 + 1][row] = v.y;
      As[kq * 4 + 2][row] = v.z;
      As[kq * 4 + 3][row] = v.w;
    }
    for (int t = tid; t < BN * 4; t += 256) {
      const int row = t >> 2, kq = t & 3;
      const float4 v = *reinterpret_cast<const float4*>(
          Bw + (size_t)(n0 + row) * ldb + k0 + kq * 4);
      Bs[kq * 4 + 0][row] = v.x;
      Bs[kq * 4 + 1][row] = v.y;
      Bs[kq * 4 + 2][row] = v.z;
      Bs[kq * 4 + 3][row] = v.w;
    }
    __syncthreads();
    #pragma unroll
    for (int k = 0; k < BK; ++k) {
      float a[TM], b[TN];
      #pragma unroll
      for (int i = 0; i < TM; ++i) a[i] = As[k][ty * TM + i];
      #pragma unroll
      for (int j = 0; j < TN; ++j) b[j] = Bs[k][tx * TN + j];
      #pragma unroll
      for (int i = 0; i < TM; ++i)
        #pragma unroll
        for (int j = 0; j < TN; ++j)
          acc[i][j] = fmaf(a[i], b[j], acc[i][j]);
    }
  }

  #pragma unroll
  for (int i = 0; i < TM; ++i) {
    const int cm = m0 + ty * TM + i;
    #pragma unroll
    for (int j = 0; j < TN; ++j) {
      const int cn = n0 + tx * TN + j;
      float v = acc[i][j];
      if (EPI == 1) {
        v += bias[cn];
        v = (v > 20.f) ? v : log1pf(__expf(v));   // softplus
      }
      C[(size_t)cm * ldc + cn] = v;
    }
  }
}

// ---------------------------------------------------------------------------
// Depthwise causal conv1d (k=4) + bias + SiLU.
// ---------------------------------------------------------------------------
__global__ __launch_bounds__(256)
void conv_silu(const float* __restrict__ xz, const float* __restrict__ cw,
               const float* __restrict__ cb, float* __restrict__ xc) {
  const int idx = blockIdx.x * 256 + threadIdx.x;
  if (idx >= MM * DINNER) return;
  const int d = idx & (DINNER - 1);
  const int m = idx >> 11;
  const int l = m & (LL - 1);
  const int b = m >> 10;
  float acc = cb[d];
  #pragma unroll
  for (int j = 0; j < DCONV; ++j) {
    const int ll = l - (DCONV - 1) + j;
    if (ll >= 0)
      acc = fmaf(xz[((size_t)(b * LL + ll) << 12) + d], cw[d * DCONV + j], acc);
  }
  xc[idx] = acc / (1.f + __expf(-acc));   // silu
}

// ---------------------------------------------------------------------------
// Chunked parallel selective scan.
//   h_t = a_t h_{t-1} + bu_t  composes associatively:
//   Pass A: per-chunk local scan from 0 -> (hend, aprod) per (b,chunk,d,n)
//   Pass B: serial combine over 16 chunks -> hin per (b,chunk,d,n)
//   Pass C: per-chunk rescan from hin, with y epilogue.
// Block (passes A/C) = 1 wave: t -> ch = t>>2 (16 channels), q = t&3 (4 states).
// ---------------------------------------------------------------------------
__device__ __forceinline__ void stage_tile(const float* g, int stride,
                                           float* ldst, int lane) {
  const int r  = lane >> 2;
  const int q4 = (lane & 3) * 4;
  #pragma unroll
  for (int i = 0; i < 4; ++i) {
    __builtin_amdgcn_global_load_lds(
        AS1(g + (size_t)(i * 16 + r) * stride + q4),
        AS3(ldst + i * 256), 16, 0, 0);
  }
}

__device__ __forceinline__ float quad_sum(float v) {
  int i = __float_as_int(v);
  v += __int_as_float(__builtin_amdgcn_update_dpp(0, i, 0xB1, 0xf, 0xf, true)); // xor 1
  i = __float_as_int(v);
  v += __int_as_float(__builtin_amdgcn_update_dpp(0, i, 0x4E, 0xf, 0xf, true)); // xor 2
  return v;
}

// Pass A: chunk-local end state + decay product.
__global__ __launch_bounds__(64)
void scan_chunk_state(const float* __restrict__ delta, const float* __restrict__ xc,
                      const float* __restrict__ xdbl, const float* __restrict__ A_log,
                      float* __restrict__ hend, float* __restrict__ aprod) {
  __shared__ float dT[CL][16];
  __shared__ float xT[CL][16];
  __shared__ float bT[CL][16];

  const int idx = blockIdx.x;          // (b*128 + dg)*16 + c
  const int c  = idx & 15;
  const int dg = (idx >> 4) & 127;
  const int b  = idx >> 11;
  const int t  = threadIdx.x;
  const int ch = t >> 2;
  const int q  = t & 3;
  const int d  = dg * 16 + ch;

  const size_t r0 = (size_t)b * LL + (size_t)c * CL;
  stage_tile(delta + r0 * DINNER + dg * 16, DINNER, &dT[0][0], t);
  stage_tile(xc    + r0 * DINNER + dg * 16, DINNER, &xT[0][0], t);
  stage_tile(xdbl  + r0 * 96 + DTRANK,          96, &bT[0][0], t);

  float Adn[4];
  #pragma unroll
  for (int j = 0; j < 4; ++j)
    Adn[j] = -__expf(A_log[d * DSTATE + 4 * q + j]);
  float h0 = 0.f, h1 = 0.f, h2 = 0.f, h3 = 0.f;
  float p0 = 1.f, p1 = 1.f, p2 = 1.f, p3 = 1.f;

  __syncthreads();

  #pragma unroll 8
  for (int l = 0; l < CL; ++l) {
    const float dv = dT[l][ch];
    const float xv = xT[l][ch];
    const float4 B4 = *reinterpret_cast<const float4*>(&bT[l][4 * q]);
    const float dvx = dv * xv;
    const float a0 = __expf(dv * Adn[0]);
    const float a1 = __expf(dv * Adn[1]);
    const float a2 = __expf(dv * Adn[2]);
    const float a3 = __expf(dv * Adn[3]);
    h0 = fmaf(a0, h0, dvx * B4.x);  p0 *= a0;
    h1 = fmaf(a1, h1, dvx * B4.y);  p1 *= a1;
    h2 = fmaf(a2, h2, dvx * B4.z);  p2 *= a2;
    h3 = fmaf(a3, h3, dvx * B4.w);  p3 *= a3;
  }

  const size_t base = (((size_t)(b * NCH + c) * DINNER) + d) * DSTATE + 4 * q;
  *reinterpret_cast<float4*>(hend  + base) = (float4){h0, h1, h2, h3};
  *reinterpret_cast<float4*>(aprod + base) = (float4){p0, p1, p2, p3};
}

// Pass B: serial combine across chunks (one thread per (b,d,n)).
__global__ __launch_bounds__(256)
void scan_combine(const float* __restrict__ hend, const float* __restrict__ aprod,
                  float* __restrict__ hin) {
  const int tid = blockIdx.x * 256 + threadIdx.x;   // 65536 total
  const size_t cstride = (size_t)DINNER * DSTATE;   // 32768
  const size_t base = (size_t)(tid >> 15) * NCH * cstride + (tid & 32767);
  float h = 0.f;
  hin[base] = 0.f;
  #pragma unroll
  for (int c = 0; c < NCH - 1; ++c) {
    h = fmaf(aprod[base + (size_t)c * cstride], h, hend[base + (size_t)c * cstride]);
    hin[base + (size_t)(c + 1) * cstride] = h;
  }
}

// Pass C: rescan chunk from hin with full epilogue -> y (bf16 hi/lo).
__global__ __launch_bounds__(64)
void scan_apply(const float* __restrict__ delta, const float* __restrict__ xc,
                const float* __restrict__ xdbl, const float* __restrict__ xz,
                const float* __restrict__ A_log, const float* __restrict__ Dp,
                const float* __restrict__ hin,
                ushort* __restrict__ yh, ushort* __restrict__ yl) {
  __shared__ float dT[CL][16];
  __shared__ float xT[CL][16];
  __shared__ float bT[CL][16];
  __shared__ float cT[CL][16];
  __shared__ float zT[CL][16];

  const int idx = blockIdx.x;
  const int c  = idx & 15;
  const int dg = (idx >> 4) & 127;
  const int b  = idx >> 11;
  const int t  = threadIdx.x;
  const int ch = t >> 2;
  const int q  = t & 3;
  const int d  = dg * 16 + ch;

  const size_t r0 = (size_t)b * LL + (size_t)c * CL;
  stage_tile(delta + r0 * DINNER + dg * 16, DINNER, &dT[0][0], t);
  stage_tile(xc    + r0 * DINNER + dg * 16, DINNER, &xT[0][0], t);
  stage_tile(xdbl  + r0 * 96 + DTRANK,          96, &bT[0][0], t);
  stage_tile(xdbl  + r0 * 96 + DTRANK + DSTATE, 96, &cT[0][0], t);
  stage_tile(xz    + (r0 << 12) + DINNER + dg * 16, 4096, &zT[0][0], t);

  float Adn[4];
  #pragma unroll
  for (int j = 0; j < 4; ++j)
    Adn[j] = -__expf(A_log[d * DSTATE + 4 * q + j]);
  const float Dd = Dp[d];

  const size_t base = (((size_t)(b * NCH + c) * DINNER) + d) * DSTATE + 4 * q;
  const float4 h4 = *reinterpret_cast<const float4*>(hin + base);
  float h0 = h4.x, h1 = h4.y, h2 = h4.z, h3 = h4.w;

  __syncthreads();

  #pragma unroll 8
  for (int l = 0; l < CL; ++l) {
    const float dv = dT[l][ch];
    const float xv = xT[l][ch];
    const float4 B4 = *reinterpret_cast<const float4*>(&bT[l][4 * q]);
    const float4 C4 = *reinterpret_cast<const float4*>(&cT[l][4 * q]);
    const float dvx = dv * xv;
    const float a0 = __expf(dv * Adn[0]);
    const float a1 = __expf(dv * Adn[1]);
    const float a2 = __expf(dv * Adn[2]);
    const float a3 = __expf(dv * Adn[3]);
    h0 = fmaf(a0, h0, dvx * B4.x);
    h1 = fmaf(a1, h1, dvx * B4.y);
    h2 = fmaf(a2, h2, dvx * B4.z);
    h3 = fmaf(a3, h3, dvx * B4.w);
    float ys = fmaf(h0, C4.x, fmaf(h1, C4.y, fmaf(h2, C4.z, h3 * C4.w)));
    ys = quad_sum(ys);
    if (q == 0) {
      const float zv = zT[l][ch];
      const float g  = zv / (1.f + __expf(-zv));
      const float tv = (ys + xv * Dd) * g;
      const size_t oidx = (r0 + l) * (size_t)DINNER + d;
      const ushort hh = bf16_rne(tv);
      yh[oidx] = hh;
      yl[oidx] = bf16_rne(tv - __uint_as_float((uint)hh << 16));
    }
  }
}

// ---------------------------------------------------------------------------
extern "C" void kernel_launch(void* const* d_in, const int* in_sizes, int n_in,
                              void* d_out, int out_size, void* d_ws, size_t ws_size,
                              hipStream_t stream) {
  const float* x         = (const float*)d_in[0];
  const float* in_proj_w = (const float*)d_in[1];
  const float* conv_w    = (const float*)d_in[2];
  const float* conv_b    = (const float*)d_in[3];
  const float* x_proj_w  = (const float*)d_in[4];
  const float* dt_proj_w = (const float*)d_in[5];
  const float* dt_proj_b = (const float*)d_in[6];
  const float* A_log     = (const float*)d_in[7];
  const float* Dv        = (const float*)d_in[8];
  const float* out_proj_w= (const float*)d_in[9];
  float* out = (float*)d_out;

  float* ws    = (float*)d_ws;
  float* xz    = ws;                          // [2048][4096] f32
  float* xc    = xz    + (size_t)MM * 4096;   // [2048][2048] f32
  float* xdbl  = xc    + (size_t)MM * DINNER; // [2048][96]   f32
  float* delta = xdbl  + (size_t)MM * 96;     // [2048][2048] f32
  ushort* us   = (ushort*)(delta + (size_t)MM * DINNER);
  ushort* yhp  = us;                           // [2048][2048] bf16 hi
  ushort* ylp  = yhp + (size_t)MM * DINNER;    // [2048][2048] bf16 lo
  ushort* xh   = ylp + (size_t)MM * DINNER;    // [2048][1024]
  ushort* xl   = xh  + (size_t)MM * DMODEL;
  ushort* wih  = xl  + (size_t)MM * DMODEL;    // [4096][1024]
  ushort* wil  = wih + (size_t)4096 * DMODEL;
  ushort* woh  = wil + (size_t)4096 * DMODEL;  // [1024][2048]
  ushort* wol  = woh + (size_t)DMODEL * DINNER;

  // chunk-state arrays alias the wih/wil region (dead after in_proj GEMM):
  // 3 x [2][16][2048][16] f32 = 12.6 MB <= 16.8 MB.
  float* hend  = (float*)wih;
  float* aprod = hend  + (size_t)BB * NCH * DINNER * DSTATE;
  float* hin   = aprod + (size_t)BB * NCH * DINNER * DSTATE;

  const dim3 blk(256);

  // 0) precision splits
  split_hl<<<dim3((MM * DMODEL) / 1024), blk, 0, stream>>>(x, xh, xl, MM * DMODEL);
  split_hl<<<dim3((4096 * DMODEL) / 1024), blk, 0, stream>>>(in_proj_w, wih, wil, 4096 * DMODEL);
  split_hl<<<dim3((DMODEL * DINNER) / 1024), blk, 0, stream>>>(out_proj_w, woh, wol, DMODEL * DINNER);

  // 1) in_proj (MFMA split-bf16): xz = x @ in_proj_w^T  (M=2048,N=4096,K=1024)
  gemm_hl_mfma<<<dim3(4096 / 128, MM / 128), blk, 0, stream>>>(
      xh, xl, wih, wil, xz, MM, 4096, DMODEL);

  // 2) causal depthwise conv + silu -> xc
  conv_silu<<<dim3((MM * DINNER) / 256), blk, 0, stream>>>(xz, conv_w, conv_b, xc);

  // 3) x_proj: xdbl = xc @ x_proj_w^T  (M=2048, N=96, K=2048)
  gemm_nt<64,32,4,2,0><<<dim3(96/32, MM/64), blk, 0, stream>>>(
      xc, x_proj_w, xdbl, nullptr, MM, 96, DINNER, DINNER, DINNER, 96);

  // 4) dt_proj + softplus
  gemm_nt<128,128,8,8,1><<<dim3(DINNER/128, MM/128), blk, 0, stream>>>(
      xdbl, dt_proj_w, delta, dt_proj_b, MM, DINNER, DTRANK, 96, DTRANK, DINNER);

  // 5) chunked parallel scan (A: local states, B: combine, C: apply+epilogue)
  scan_chunk_state<<<dim3(BB * 128 * NCH), dim3(64), 0, stream>>>(
      delta, xc, xdbl, A_log, hend, aprod);
  scan_combine<<<dim3(BB * DINNER * DSTATE / 256), blk, 0, stream>>>(
      hend, aprod, hin);
  scan_apply<<<dim3(BB * 128 * NCH), dim3(64), 0, stream>>>(
      delta, xc, xdbl, xz, A_log, Dv, hin, yhp, ylp);

  // 6) out_proj (MFMA split-bf16): out = y @ out_proj_w^T (M=2048,N=1024,K=2048)
  gemm_hl_mfma<<<dim3(DMODEL / 128, MM / 128), blk, 0, stream>>>(
      yhp, ylp, woh, wol, out, MM, DMODEL, DINNER);
}

// Round 5
// 261.602 us; speedup vs baseline: 5.1506x; 1.4998x over previous
//
#include <hip/hip_runtime.h>
#include <math.h>
#include <stdint.h>

#define DMODEL 1024
#define DINNER 2048
#define DCONV  4
#define DSTATE 16
#define DTRANK 64
#define BB 2
#define LL 1024
#define MM (BB * LL)            // 2048 rows in all GEMMs

#define CL  64                  // scan chunk length
#define NCH (LL / CL)           // 16 chunks

#define AS1(p) ((__attribute__((address_space(1))) void*)(void*)(p))
#define AS3(p) ((__attribute__((address_space(3))) void*)(void*)(p))

typedef __attribute__((ext_vector_type(8))) short bf16x8;
typedef __attribute__((ext_vector_type(4))) float f32x4;

__device__ __forceinline__ ushort bf16_rne(float f) {
  uint32_t u = __float_as_uint(f);
  uint32_t r = (u + 0x7fffu + ((u >> 16) & 1u)) >> 16;
  return (ushort)r;
}

// ---------------------------------------------------------------------------
// f32 -> (hi, lo) bf16 planes.  n % 4 == 0, contiguous.
// ---------------------------------------------------------------------------
__global__ __launch_bounds__(256)
void split_hl(const float* __restrict__ in, ushort* __restrict__ hi,
              ushort* __restrict__ lo, int n) {
  const int i = (blockIdx.x * 256 + threadIdx.x) * 4;
  if (i >= n) return;
  const float4 v = *reinterpret_cast<const float4*>(in + i);
  ushort4 h, l;
  h.x = bf16_rne(v.x); l.x = bf16_rne(v.x - __uint_as_float((uint)h.x << 16));
  h.y = bf16_rne(v.y); l.y = bf16_rne(v.y - __uint_as_float((uint)h.y << 16));
  h.z = bf16_rne(v.z); l.z = bf16_rne(v.z - __uint_as_float((uint)h.z << 16));
  h.w = bf16_rne(v.w); l.w = bf16_rne(v.w - __uint_as_float((uint)h.w << 16));
  *reinterpret_cast<ushort4*>(hi + i) = h;
  *reinterpret_cast<ushort4*>(lo + i) = l;
}

// dt columns (xdbl[:, 0:64], row stride 96) -> packed [2048][64] bf16 hi/lo
__global__ __launch_bounds__(256)
void split_dt(const float* __restrict__ xdbl, ushort* __restrict__ hi,
              ushort* __restrict__ lo) {
  const int i = blockIdx.x * 256 + threadIdx.x;   // one float4 each, 32768 total
  if (i >= MM * 16) return;
  const int m  = i >> 4;
  const int c4 = (i & 15) * 4;
  const float4 v = *reinterpret_cast<const float4*>(xdbl + (size_t)m * 96 + c4);
  ushort4 h, l;
  h.x = bf16_rne(v.x); l.x = bf16_rne(v.x - __uint_as_float((uint)h.x << 16));
  h.y = bf16_rne(v.y); l.y = bf16_rne(v.y - __uint_as_float((uint)h.y << 16));
  h.z = bf16_rne(v.z); l.z = bf16_rne(v.z - __uint_as_float((uint)h.z << 16));
  h.w = bf16_rne(v.w); l.w = bf16_rne(v.w - __uint_as_float((uint)h.w << 16));
  *reinterpret_cast<ushort4*>(hi + (size_t)m * 64 + c4) = h;
  *reinterpret_cast<ushort4*>(lo + (size_t)m * 64 + c4) = l;
}

// ---------------------------------------------------------------------------
// Split-precision bf16 MFMA NT GEMM.  EPI 0: C=acc.  EPI 1: C=softplus(acc+bias[n]).
// 128x128 tile, BK=32, 4 waves, global_load_lds staging, XOR-swizzled LDS.
// ---------------------------------------------------------------------------
__device__ __forceinline__ int swz4(int r) { return (r & 3) ^ ((r >> 2) & 3); }

template<int EPI>
__global__ __launch_bounds__(256)
void gemm_hl_mfma(const ushort* __restrict__ Ahg, const ushort* __restrict__ Alg,
                  const ushort* __restrict__ Bhg, const ushort* __restrict__ Blg,
                  float* __restrict__ C, const float* __restrict__ bias,
                  int M, int N, int K) {
  __shared__ ushort Ah[128][32];
  __shared__ ushort Al[128][32];
  __shared__ ushort Bh[128][32];
  __shared__ ushort Bl[128][32];

  const int tid  = threadIdx.x;
  const int wave = tid >> 6;
  const int lane = tid & 63;
  const int m0 = blockIdx.y * 128;
  const int n0 = blockIdx.x * 128;
  const int wm = (wave >> 1) * 64;
  const int wn = (wave & 1) * 64;

  f32x4 acc[4][4];
  #pragma unroll
  for (int i = 0; i < 4; ++i)
    #pragma unroll
    for (int j = 0; j < 4; ++j)
      acc[i][j] = (f32x4){0.f, 0.f, 0.f, 0.f};

  const ushort* gsrc; ushort* dst; int row0;
  if      (wave == 0) { gsrc = Ahg; dst = &Ah[0][0]; row0 = m0; }
  else if (wave == 1) { gsrc = Alg; dst = &Al[0][0]; row0 = m0; }
  else if (wave == 2) { gsrc = Bhg; dst = &Bh[0][0]; row0 = n0; }
  else                { gsrc = Blg; dst = &Bl[0][0]; row0 = n0; }

  const int lr = lane >> 2;
  const int ls = lane & 3;
  const int fr = lane & 15;
  const int q  = lane >> 4;

  for (int k0 = 0; k0 < K; k0 += 32) {
    if (k0) __syncthreads();
    #pragma unroll
    for (int seg = 0; seg < 8; ++seg) {
      const int rho = seg * 16 + lr;
      const int ks  = (ls ^ swz4(rho)) * 8;
      __builtin_amdgcn_global_load_lds(
          AS1(gsrc + (size_t)(row0 + rho) * K + k0 + ks),
          AS3(dst + seg * 512), 16, 0, 0);
    }
    __syncthreads();

    bf16x8 ah[4], al[4], bh[4], bl[4];
    #pragma unroll
    for (int f = 0; f < 4; ++f) {
      { const int r = wm + f * 16 + fr; const int s = 8 * (q ^ swz4(r));
        ah[f] = *reinterpret_cast<const bf16x8*>(&Ah[r][s]);
        al[f] = *reinterpret_cast<const bf16x8*>(&Al[r][s]); }
      { const int r = wn + f * 16 + fr; const int s = 8 * (q ^ swz4(r));
        bh[f] = *reinterpret_cast<const bf16x8*>(&Bh[r][s]);
        bl[f] = *reinterpret_cast<const bf16x8*>(&Bl[r][s]); }
    }
    #pragma unroll
    for (int i = 0; i < 4; ++i)
      #pragma unroll
      for (int j = 0; j < 4; ++j) {
        acc[i][j] = __builtin_amdgcn_mfma_f32_16x16x32_bf16(ah[i], bh[j], acc[i][j], 0, 0, 0);
        acc[i][j] = __builtin_amdgcn_mfma_f32_16x16x32_bf16(al[i], bh[j], acc[i][j], 0, 0, 0);
        acc[i][j] = __builtin_amdgcn_mfma_f32_16x16x32_bf16(ah[i], bl[j], acc[i][j], 0, 0, 0);
      }
  }

  const int cr = (lane >> 4) * 4;
  const int cc = lane & 15;
  #pragma unroll
  for (int i = 0; i < 4; ++i)
    #pragma unroll
    for (int j = 0; j < 4; ++j) {
      const int cn = n0 + wn + j * 16 + cc;
      const float bj = (EPI == 1) ? bias[cn] : 0.f;
      const size_t base = (size_t)(m0 + wm + i * 16 + cr) * N + cn;
      #pragma unroll
      for (int r = 0; r < 4; ++r) {
        float v = acc[i][j][r];
        if (EPI == 1) {
          v += bj;
          v = fmaxf(v, 0.f) + __logf(1.f + __expf(-fabsf(v)));   // softplus
        }
        C[base + (size_t)r * N] = v;
      }
    }
}

// ---------------------------------------------------------------------------
// Split-K f32 NT GEMM partials (x_proj): P[z] = A[:, zK:zK+KS] @ B[:, zK:]^T
// ---------------------------------------------------------------------------
template<int BM, int BN, int TM, int TN, int KSLICE>
__global__ __launch_bounds__(256)
void gemm_nt_part(const float* __restrict__ A, const float* __restrict__ Bw,
                  float* __restrict__ P, int M, int N, int lda, int ldb) {
  constexpr int BK  = 16;
  constexpr int NTX = BN / TN;
  constexpr int NTY = BM / TM;
  static_assert(NTX * NTY == 256, "thread tile mismatch");
  __shared__ float As[BK][BM + 4];
  __shared__ float Bs[BK][BN + 4];

  const int tid = threadIdx.x;
  const int m0  = blockIdx.y * BM;
  const int n0  = blockIdx.x * BN;
  const int kb  = blockIdx.z * KSLICE;
  const int tx  = tid % NTX;
  const int ty  = tid / NTX;

  float acc[TM][TN] = {};

  for (int k0 = kb; k0 < kb + KSLICE; k0 += BK) {
    __syncthreads();
    for (int t = tid; t < BM * 4; t += 256) {
      const int row = t >> 2, kq = t & 3;
      const float4 v = *reinterpret_cast<const float4*>(
          A + (size_t)(m0 + row) * lda + k0 + kq * 4);
      As[kq * 4 + 0][row] = v.x;
      As[kq * 4 + 1][row] = v.y;
      As[kq * 4 + 2][row] = v.z;
      As[kq * 4 + 3][row] = v.w;
    }
    for (int t = tid; t < BN * 4; t += 256) {
      const int row = t >> 2, kq = t & 3;
      const float4 v = *reinterpret_cast<const float4*>(
          Bw + (size_t)(n0 + row) * ldb + k0 + kq * 4);
      Bs[kq * 4 + 0][row] = v.x;
      Bs[kq * 4 + 1][row] = v.y;
      Bs[kq * 4 + 2][row] = v.z;
      Bs[kq * 4 + 3][row] = v.w;
    }
    __syncthreads();
    #pragma unroll
    for (int k = 0; k < BK; ++k) {
      float a[TM], b[TN];
      #pragma unroll
      for (int i = 0; i < TM; ++i) a[i] = As[k][ty * TM + i];
      #pragma unroll
      for (int j = 0; j < TN; ++j) b[j] = Bs[k][tx * TN + j];
      #pragma unroll
      for (int i = 0; i < TM; ++i)
        #pragma unroll
        for (int j = 0; j < TN; ++j)
          acc[i][j] = fmaf(a[i], b[j], acc[i][j]);
    }
  }

  float* out = P + (size_t)blockIdx.z * M * N;
  #pragma unroll
  for (int i = 0; i < TM; ++i)
    #pragma unroll
    for (int j = 0; j < TN; ++j)
      out[(size_t)(m0 + ty * TM + i) * N + n0 + tx * TN + j] = acc[i][j];
}

__global__ __launch_bounds__(256)
void xproj_reduce(const float* __restrict__ part, float* __restrict__ xdbl) {
  const int i = (blockIdx.x * 256 + threadIdx.x) * 4;   // over 2048*96
  if (i >= MM * 96) return;
  float4 s = *reinterpret_cast<const float4*>(part + i);
  #pragma unroll
  for (int z = 1; z < 8; ++z) {
    const float4 v = *reinterpret_cast<const float4*>(part + (size_t)z * MM * 96 + i);
    s.x += v.x; s.y += v.y; s.z += v.z; s.w += v.w;
  }
  *reinterpret_cast<float4*>(xdbl + i) = s;
}

// ---------------------------------------------------------------------------
// Depthwise causal conv1d (k=4) + bias + SiLU.
// ---------------------------------------------------------------------------
__global__ __launch_bounds__(256)
void conv_silu(const float* __restrict__ xz, const float* __restrict__ cw,
               const float* __restrict__ cb, float* __restrict__ xc) {
  const int idx = blockIdx.x * 256 + threadIdx.x;
  if (idx >= MM * DINNER) return;
  const int d = idx & (DINNER - 1);
  const int m = idx >> 11;
  const int l = m & (LL - 1);
  const int b = m >> 10;
  float acc = cb[d];
  #pragma unroll
  for (int j = 0; j < DCONV; ++j) {
    const int ll = l - (DCONV - 1) + j;
    if (ll >= 0)
      acc = fmaf(xz[((size_t)(b * LL + ll) << 12) + d], cw[d * DCONV + j], acc);
  }
  xc[idx] = acc / (1.f + __expf(-acc));   // silu
}

// ---------------------------------------------------------------------------
// Chunked parallel selective scan (3 passes), unchanged from round 4.
// ---------------------------------------------------------------------------
__device__ __forceinline__ void stage_tile(const float* g, int stride,
                                           float* ldst, int lane) {
  const int r  = lane >> 2;
  const int q4 = (lane & 3) * 4;
  #pragma unroll
  for (int i = 0; i < 4; ++i) {
    __builtin_amdgcn_global_load_lds(
        AS1(g + (size_t)(i * 16 + r) * stride + q4),
        AS3(ldst + i * 256), 16, 0, 0);
  }
}

__device__ __forceinline__ float quad_sum(float v) {
  int i = __float_as_int(v);
  v += __int_as_float(__builtin_amdgcn_update_dpp(0, i, 0xB1, 0xf, 0xf, true)); // xor 1
  i = __float_as_int(v);
  v += __int_as_float(__builtin_amdgcn_update_dpp(0, i, 0x4E, 0xf, 0xf, true)); // xor 2
  return v;
}

__global__ __launch_bounds__(64)
void scan_chunk_state(const float* __restrict__ delta, const float* __restrict__ xc,
                      const float* __restrict__ xdbl, const float* __restrict__ A_log,
                      float* __restrict__ hend, float* __restrict__ aprod) {
  __shared__ float dT[CL][16];
  __shared__ float xT[CL][16];
  __shared__ float bT[CL][16];

  const int idx = blockIdx.x;          // (b*128 + dg)*16 + c
  const int c  = idx & 15;
  const int dg = (idx >> 4) & 127;
  const int b  = idx >> 11;
  const int t  = threadIdx.x;
  const int ch = t >> 2;
  const int q  = t & 3;
  const int d  = dg * 16 + ch;

  const size_t r0 = (size_t)b * LL + (size_t)c * CL;
  stage_tile(delta + r0 * DINNER + dg * 16, DINNER, &dT[0][0], t);
  stage_tile(xc    + r0 * DINNER + dg * 16, DINNER, &xT[0][0], t);
  stage_tile(xdbl  + r0 * 96 + DTRANK,          96, &bT[0][0], t);

  float Adn[4];
  #pragma unroll
  for (int j = 0; j < 4; ++j)
    Adn[j] = -__expf(A_log[d * DSTATE + 4 * q + j]);
  float h0 = 0.f, h1 = 0.f, h2 = 0.f, h3 = 0.f;
  float p0 = 1.f, p1 = 1.f, p2 = 1.f, p3 = 1.f;

  __syncthreads();

  #pragma unroll 8
  for (int l = 0; l < CL; ++l) {
    const float dv = dT[l][ch];
    const float xv = xT[l][ch];
    const float4 B4 = *reinterpret_cast<const float4*>(&bT[l][4 * q]);
    const float dvx = dv * xv;
    const float a0 = __expf(dv * Adn[0]);
    const float a1 = __expf(dv * Adn[1]);
    const float a2 = __expf(dv * Adn[2]);
    const float a3 = __expf(dv * Adn[3]);
    h0 = fmaf(a0, h0, dvx * B4.x);  p0 *= a0;
    h1 = fmaf(a1, h1, dvx * B4.y);  p1 *= a1;
    h2 = fmaf(a2, h2, dvx * B4.z);  p2 *= a2;
    h3 = fmaf(a3, h3, dvx * B4.w);  p3 *= a3;
  }

  const size_t base = (((size_t)(b * NCH + c) * DINNER) + d) * DSTATE + 4 * q;
  *reinterpret_cast<float4*>(hend  + base) = (float4){h0, h1, h2, h3};
  *reinterpret_cast<float4*>(aprod + base) = (float4){p0, p1, p2, p3};
}

__global__ __launch_bounds__(256)
void scan_combine(const float* __restrict__ hend, const float* __restrict__ aprod,
                  float* __restrict__ hin) {
  const int tid = blockIdx.x * 256 + threadIdx.x;   // 65536 total
  const size_t cstride = (size_t)DINNER * DSTATE;   // 32768
  const size_t base = (size_t)(tid >> 15) * NCH * cstride + (tid & 32767);
  float h = 0.f;
  hin[base] = 0.f;
  #pragma unroll
  for (int c = 0; c < NCH - 1; ++c) {
    h = fmaf(aprod[base + (size_t)c * cstride], h, hend[base + (size_t)c * cstride]);
    hin[base + (size_t)(c + 1) * cstride] = h;
  }
}

__global__ __launch_bounds__(64)
void scan_apply(const float* __restrict__ delta, const float* __restrict__ xc,
                const float* __restrict__ xdbl, const float* __restrict__ xz,
                const float* __restrict__ A_log, const float* __restrict__ Dp,
                const float* __restrict__ hin,
                ushort* __restrict__ yh, ushort* __restrict__ yl) {
  __shared__ float dT[CL][16];
  __shared__ float xT[CL][16];
  __shared__ float bT[CL][16];
  __shared__ float cT[CL][16];
  __shared__ float zT[CL][16];

  const int idx = blockIdx.x;
  const int c  = idx & 15;
  const int dg = (idx >> 4) & 127;
  const int b  = idx >> 11;
  const int t  = threadIdx.x;
  const int ch = t >> 2;
  const int q  = t & 3;
  const int d  = dg * 16 + ch;

  const size_t r0 = (size_t)b * LL + (size_t)c * CL;
  stage_tile(delta + r0 * DINNER + dg * 16, DINNER, &dT[0][0], t);
  stage_tile(xc    + r0 * DINNER + dg * 16, DINNER, &xT[0][0], t);
  stage_tile(xdbl  + r0 * 96 + DTRANK,          96, &bT[0][0], t);
  stage_tile(xdbl  + r0 * 96 + DTRANK + DSTATE, 96, &cT[0][0], t);
  stage_tile(xz    + (r0 << 12) + DINNER + dg * 16, 4096, &zT[0][0], t);

  float Adn[4];
  #pragma unroll
  for (int j = 0; j < 4; ++j)
    Adn[j] = -__expf(A_log[d * DSTATE + 4 * q + j]);
  const float Dd = Dp[d];

  const size_t base = (((size_t)(b * NCH + c) * DINNER) + d) * DSTATE + 4 * q;
  const float4 h4 = *reinterpret_cast<const float4*>(hin + base);
  float h0 = h4.x, h1 = h4.y, h2 = h4.z, h3 = h4.w;

  __syncthreads();

  #pragma unroll 8
  for (int l = 0; l < CL; ++l) {
    const float dv = dT[l][ch];
    const float xv = xT[l][ch];
    const float4 B4 = *reinterpret_cast<const float4*>(&bT[l][4 * q]);
    const float4 C4 = *reinterpret_cast<const float4*>(&cT[l][4 * q]);
    const float dvx = dv * xv;
    const float a0 = __expf(dv * Adn[0]);
    const float a1 = __expf(dv * Adn[1]);
    const float a2 = __expf(dv * Adn[2]);
    const float a3 = __expf(dv * Adn[3]);
    h0 = fmaf(a0, h0, dvx * B4.x);
    h1 = fmaf(a1, h1, dvx * B4.y);
    h2 = fmaf(a2, h2, dvx * B4.z);
    h3 = fmaf(a3, h3, dvx * B4.w);
    float ys = fmaf(h0, C4.x, fmaf(h1, C4.y, fmaf(h2, C4.z, h3 * C4.w)));
    ys = quad_sum(ys);
    if (q == 0) {
      const float zv = zT[l][ch];
      const float g  = zv / (1.f + __expf(-zv));
      const float tv = (ys + xv * Dd) * g;
      const size_t oidx = (r0 + l) * (size_t)DINNER + d;
      const ushort hh = bf16_rne(tv);
      yh[oidx] = hh;
      yl[oidx] = bf16_rne(tv - __uint_as_float((uint)hh << 16));
    }
  }
}

// ---------------------------------------------------------------------------
extern "C" void kernel_launch(void* const* d_in, const int* in_sizes, int n_in,
                              void* d_out, int out_size, void* d_ws, size_t ws_size,
                              hipStream_t stream) {
  const float* x         = (const float*)d_in[0];
  const float* in_proj_w = (const float*)d_in[1];
  const float* conv_w    = (const float*)d_in[2];
  const float* conv_b    = (const float*)d_in[3];
  const float* x_proj_w  = (const float*)d_in[4];
  const float* dt_proj_w = (const float*)d_in[5];
  const float* dt_proj_b = (const float*)d_in[6];
  const float* A_log     = (const float*)d_in[7];
  const float* Dv        = (const float*)d_in[8];
  const float* out_proj_w= (const float*)d_in[9];
  float* out = (float*)d_out;

  float* ws    = (float*)d_ws;
  float* xz    = ws;                          // [2048][4096] f32
  float* xc    = xz    + (size_t)MM * 4096;   // [2048][2048] f32
  float* xdbl  = xc    + (size_t)MM * DINNER; // [2048][96]   f32
  float* delta = xdbl  + (size_t)MM * 96;     // [2048][2048] f32
  ushort* us   = (ushort*)(delta + (size_t)MM * DINNER);
  ushort* yhp  = us;                           // [2048][2048] bf16 hi
  ushort* ylp  = yhp + (size_t)MM * DINNER;    // [2048][2048] bf16 lo
  ushort* xh   = ylp + (size_t)MM * DINNER;    // [2048][1024]
  ushort* xl   = xh  + (size_t)MM * DMODEL;
  ushort* wih  = xl  + (size_t)MM * DMODEL;    // [4096][1024]
  ushort* wil  = wih + (size_t)4096 * DMODEL;
  ushort* woh  = wil + (size_t)4096 * DMODEL;  // [1024][2048]
  ushort* wol  = woh + (size_t)DMODEL * DINNER;

  // aliases onto dead regions:
  // hend/aprod/hin (scan) live in wih/wil (dead after in_proj GEMM)
  float* hend  = (float*)wih;
  float* aprod = hend  + (size_t)BB * NCH * DINNER * DSTATE;
  float* hin   = aprod + (size_t)BB * NCH * DINNER * DSTATE;
  // x_proj split-K partials [8][2048][96] = 6.3 MB in hend+aprod (consumed
  // by xproj_reduce before scan passes write hend/aprod)
  float* part  = hend;
  // dt hi/lo + dt_proj_w hi/lo live in xh/xl (dead after in_proj GEMM)
  ushort* dth = xh;            ushort* dtl = xl;
  ushort* wdh = xh + 131072;   ushort* wdl = xl + 131072;

  const dim3 blk(256);

  // 0) precision splits (x, weights)
  split_hl<<<dim3((MM * DMODEL) / 1024), blk, 0, stream>>>(x, xh, xl, MM * DMODEL);
  split_hl<<<dim3((4096 * DMODEL) / 1024), blk, 0, stream>>>(in_proj_w, wih, wil, 4096 * DMODEL);
  split_hl<<<dim3((DMODEL * DINNER) / 1024), blk, 0, stream>>>(out_proj_w, woh, wol, DMODEL * DINNER);

  // 1) in_proj (MFMA split-bf16): xz = x @ in_proj_w^T  (M=2048,N=4096,K=1024)
  gemm_hl_mfma<0><<<dim3(4096 / 128, MM / 128), blk, 0, stream>>>(
      xh, xl, wih, wil, xz, nullptr, MM, 4096, DMODEL);

  // 2) causal depthwise conv + silu -> xc
  conv_silu<<<dim3((MM * DINNER) / 256), blk, 0, stream>>>(xz, conv_w, conv_b, xc);

  // 3) x_proj split-K: xdbl = xc @ x_proj_w^T  (M=2048, N=96, K=2048)
  gemm_nt_part<64,32,4,2,256><<<dim3(96/32, MM/64, 8), blk, 0, stream>>>(
      xc, x_proj_w, part, MM, 96, DINNER, DINNER);
  xproj_reduce<<<dim3((MM * 96) / 1024), blk, 0, stream>>>(part, xdbl);

  // 4) dt_proj (MFMA split-bf16 + softplus): delta = sp(dt @ dt_proj_w^T + b)
  split_hl<<<dim3((DINNER * DTRANK) / 1024), blk, 0, stream>>>(
      dt_proj_w, wdh, wdl, DINNER * DTRANK);
  split_dt<<<dim3((MM * 16) / 256), blk, 0, stream>>>(xdbl, dth, dtl);
  gemm_hl_mfma<1><<<dim3(DINNER / 128, MM / 128), blk, 0, stream>>>(
      dth, dtl, wdh, wdl, delta, dt_proj_b, MM, DINNER, DTRANK);

  // 5) chunked parallel scan (A: local states, B: combine, C: apply+epilogue)
  scan_chunk_state<<<dim3(BB * 128 * NCH), dim3(64), 0, stream>>>(
      delta, xc, xdbl, A_log, hend, aprod);
  scan_combine<<<dim3(BB * DINNER * DSTATE / 256), blk, 0, stream>>>(
      hend, aprod, hin);
  scan_apply<<<dim3(BB * 128 * NCH), dim3(64), 0, stream>>>(
      delta, xc, xdbl, xz, A_log, Dv, hin, yhp, ylp);

  // 6) out_proj (MFMA split-bf16): out = y @ out_proj_w^T (M=2048,N=1024,K=2048)
  gemm_hl_mfma<0><<<dim3(DMODEL / 128, MM / 128), blk, 0, stream>>>(
      yhp, ylp, woh, wol, out, nullptr, MM, DMODEL, DINNER);
}

// Round 6
// 229.303 us; speedup vs baseline: 5.8762x; 1.1409x over previous
//
#include <hip/hip_runtime.h>
#include <math.h>
#include <stdint.h>

#define DMODEL 1024
#define DINNER 2048
#define DCONV  4
#define DSTATE 16
#define DTRANK 64
#define BB 2
#define LL 1024
#define MM (BB * LL)            // 2048 rows in all GEMMs

#define CL  64                  // scan chunk length
#define NCH (LL / CL)           // 16 chunks

#define AS1(p) ((__attribute__((address_space(1))) void*)(void*)(p))
#define AS3(p) ((__attribute__((address_space(3))) void*)(void*)(p))

typedef __attribute__((ext_vector_type(8))) short bf16x8;
typedef __attribute__((ext_vector_type(4))) float f32x4;

__device__ __forceinline__ ushort bf16_rne(float f) {
  uint32_t u = __float_as_uint(f);
  uint32_t r = (u + 0x7fffu + ((u >> 16) & 1u)) >> 16;
  return (ushort)r;
}

// ---------------------------------------------------------------------------
// f32 -> (hi, lo) bf16 planes.  n % 4 == 0, contiguous.
// ---------------------------------------------------------------------------
__global__ __launch_bounds__(256)
void split_hl(const float* __restrict__ in, ushort* __restrict__ hi,
              ushort* __restrict__ lo, int n) {
  const int i = (blockIdx.x * 256 + threadIdx.x) * 4;
  if (i >= n) return;
  const float4 v = *reinterpret_cast<const float4*>(in + i);
  ushort4 h, l;
  h.x = bf16_rne(v.x); l.x = bf16_rne(v.x - __uint_as_float((uint)h.x << 16));
  h.y = bf16_rne(v.y); l.y = bf16_rne(v.y - __uint_as_float((uint)h.y << 16));
  h.z = bf16_rne(v.z); l.z = bf16_rne(v.z - __uint_as_float((uint)h.z << 16));
  h.w = bf16_rne(v.w); l.w = bf16_rne(v.w - __uint_as_float((uint)h.w << 16));
  *reinterpret_cast<ushort4*>(hi + i) = h;
  *reinterpret_cast<ushort4*>(lo + i) = l;
}

// dt columns (xdbl[:, 0:64], row stride 96) -> packed [2048][64] bf16 hi/lo
__global__ __launch_bounds__(256)
void split_dt(const float* __restrict__ xdbl, ushort* __restrict__ hi,
              ushort* __restrict__ lo) {
  const int i = blockIdx.x * 256 + threadIdx.x;   // one float4 each, 32768 total
  if (i >= MM * 16) return;
  const int m  = i >> 4;
  const int c4 = (i & 15) * 4;
  const float4 v = *reinterpret_cast<const float4*>(xdbl + (size_t)m * 96 + c4);
  ushort4 h, l;
  h.x = bf16_rne(v.x); l.x = bf16_rne(v.x - __uint_as_float((uint)h.x << 16));
  h.y = bf16_rne(v.y); l.y = bf16_rne(v.y - __uint_as_float((uint)h.y << 16));
  h.z = bf16_rne(v.z); l.z = bf16_rne(v.z - __uint_as_float((uint)h.z << 16));
  h.w = bf16_rne(v.w); l.w = bf16_rne(v.w - __uint_as_float((uint)h.w << 16));
  *reinterpret_cast<ushort4*>(hi + (size_t)m * 64 + c4) = h;
  *reinterpret_cast<ushort4*>(lo + (size_t)m * 64 + c4) = l;
}

// ---------------------------------------------------------------------------
// Split-precision bf16 MFMA NT GEMM, 2-phase double-buffered pipeline.
// EPI 0: C=acc.  EPI 1: C=softplus(acc+bias[n]).
// SPLITK: blockIdx.z computes K-slice z, writes C + z*M*N.
// 128x128 tile, BK=32, 4 waves, global_load_lds staging, XOR-swizzled LDS.
// ---------------------------------------------------------------------------
__device__ __forceinline__ int swz4(int r) { return (r & 3) ^ ((r >> 2) & 3); }

template<int EPI, int SPLITK>
__global__ __launch_bounds__(256)
void gemm_hl_mfma(const ushort* __restrict__ Ahg, const ushort* __restrict__ Alg,
                  const ushort* __restrict__ Bhg, const ushort* __restrict__ Blg,
                  float* __restrict__ C, const float* __restrict__ bias,
                  int M, int N, int K) {
  __shared__ ushort Ah[2][128][32];
  __shared__ ushort Al[2][128][32];
  __shared__ ushort Bh[2][128][32];
  __shared__ ushort Bl[2][128][32];

  const int tid  = threadIdx.x;
  const int wave = tid >> 6;
  const int lane = tid & 63;
  const int m0 = blockIdx.y * 128;
  const int n0 = blockIdx.x * 128;
  const int wm = (wave >> 1) * 64;
  const int wn = (wave & 1) * 64;

  const int ksl = K / SPLITK;          // K-slice length
  const int kb  = blockIdx.z * ksl;
  float* Cout   = C + (size_t)blockIdx.z * M * N;

  f32x4 acc[4][4];
  #pragma unroll
  for (int i = 0; i < 4; ++i)
    #pragma unroll
    for (int j = 0; j < 4; ++j)
      acc[i][j] = (f32x4){0.f, 0.f, 0.f, 0.f};

  const ushort* gsrc; ushort* dst; int row0;
  if      (wave == 0) { gsrc = Ahg; dst = &Ah[0][0][0]; row0 = m0; }
  else if (wave == 1) { gsrc = Alg; dst = &Al[0][0][0]; row0 = m0; }
  else if (wave == 2) { gsrc = Bhg; dst = &Bh[0][0][0]; row0 = n0; }
  else                { gsrc = Blg; dst = &Bl[0][0][0]; row0 = n0; }

  const int lr = lane >> 2;
  const int ls = lane & 3;
  const int fr = lane & 15;
  const int q  = lane >> 4;

  // stage one 128x32 plane tile into buffer bi at K offset k0 (8 loads/wave)
  auto STAGE = [&](int bi, int k0) {
    ushort* d = dst + bi * 4096;
    #pragma unroll
    for (int seg = 0; seg < 8; ++seg) {
      const int rho = seg * 16 + lr;
      const int ks  = (ls ^ swz4(rho)) * 8;
      __builtin_amdgcn_global_load_lds(
          AS1(gsrc + (size_t)(row0 + rho) * K + k0 + ks),
          AS3(d + seg * 512), 16, 0, 0);
    }
  };

  const int NT = ksl / 32;
  STAGE(0, kb);
  __syncthreads();              // drain: buf0 resident

  int cur = 0;
  for (int kt = 0; kt < NT; ++kt) {
    if (kt + 1 < NT) STAGE(cur ^ 1, kb + (kt + 1) * 32);   // prefetch in flight

    bf16x8 ah[4], al[4], bh[4], bl[4];
    #pragma unroll
    for (int f = 0; f < 4; ++f) {
      { const int r = wm + f * 16 + fr; const int s = 8 * (q ^ swz4(r));
        ah[f] = *reinterpret_cast<const bf16x8*>(&Ah[cur][r][s]);
        al[f] = *reinterpret_cast<const bf16x8*>(&Al[cur][r][s]); }
      { const int r = wn + f * 16 + fr; const int s = 8 * (q ^ swz4(r));
        bh[f] = *reinterpret_cast<const bf16x8*>(&Bh[cur][r][s]);
        bl[f] = *reinterpret_cast<const bf16x8*>(&Bl[cur][r][s]); }
    }
    #pragma unroll
    for (int i = 0; i < 4; ++i)
      #pragma unroll
      for (int j = 0; j < 4; ++j) {
        acc[i][j] = __builtin_amdgcn_mfma_f32_16x16x32_bf16(ah[i], bh[j], acc[i][j], 0, 0, 0);
        acc[i][j] = __builtin_amdgcn_mfma_f32_16x16x32_bf16(al[i], bh[j], acc[i][j], 0, 0, 0);
        acc[i][j] = __builtin_amdgcn_mfma_f32_16x16x32_bf16(ah[i], bl[j], acc[i][j], 0, 0, 0);
      }

    __syncthreads();            // drains vmcnt: prefetched tile resident
    cur ^= 1;
  }

  const int cr = (lane >> 4) * 4;
  const int cc = lane & 15;
  #pragma unroll
  for (int i = 0; i < 4; ++i)
    #pragma unroll
    for (int j = 0; j < 4; ++j) {
      const int cn = n0 + wn + j * 16 + cc;
      const float bj = (EPI == 1) ? bias[cn] : 0.f;
      const size_t base = (size_t)(m0 + wm + i * 16 + cr) * N + cn;
      #pragma unroll
      for (int r = 0; r < 4; ++r) {
        float v = acc[i][j][r];
        if (EPI == 1) {
          v += bj;
          v = fmaxf(v, 0.f) + __logf(1.f + __expf(-fabsf(v)));   // softplus
        }
        Cout[base + (size_t)r * N] = v;
      }
    }
}

// sum 2 split-K partial planes -> out
__global__ __launch_bounds__(256)
void splitk_reduce(const float* __restrict__ P, float* __restrict__ out, int n) {
  const int i = (blockIdx.x * 256 + threadIdx.x) * 4;
  if (i >= n) return;
  const float4 a = *reinterpret_cast<const float4*>(P + i);
  const float4 b = *reinterpret_cast<const float4*>(P + (size_t)n + i);
  float4 s = {a.x + b.x, a.y + b.y, a.z + b.z, a.w + b.w};
  *reinterpret_cast<float4*>(out + i) = s;
}

// ---------------------------------------------------------------------------
// Split-K f32 NT GEMM partials (x_proj): P[z] = A[:, zK:zK+KS] @ B[:, zK:]^T
// ---------------------------------------------------------------------------
template<int BM, int BN, int TM, int TN, int KSLICE>
__global__ __launch_bounds__(256)
void gemm_nt_part(const float* __restrict__ A, const float* __restrict__ Bw,
                  float* __restrict__ P, int M, int N, int lda, int ldb) {
  constexpr int BK  = 16;
  constexpr int NTX = BN / TN;
  constexpr int NTY = BM / TM;
  static_assert(NTX * NTY == 256, "thread tile mismatch");
  __shared__ float As[BK][BM + 4];
  __shared__ float Bs[BK][BN + 4];

  const int tid = threadIdx.x;
  const int m0  = blockIdx.y * BM;
  const int n0  = blockIdx.x * BN;
  const int kb  = blockIdx.z * KSLICE;
  const int tx  = tid % NTX;
  const int ty  = tid / NTX;

  float acc[TM][TN] = {};

  for (int k0 = kb; k0 < kb + KSLICE; k0 += BK) {
    __syncthreads();
    for (int t = tid; t < BM * 4; t += 256) {
      const int row = t >> 2, kq = t & 3;
      const float4 v = *reinterpret_cast<const float4*>(
          A + (size_t)(m0 + row) * lda + k0 + kq * 4);
      As[kq * 4 + 0][row] = v.x;
      As[kq * 4 + 1][row] = v.y;
      As[kq * 4 + 2][row] = v.z;
      As[kq * 4 + 3][row] = v.w;
    }
    for (int t = tid; t < BN * 4; t += 256) {
      const int row = t >> 2, kq = t & 3;
      const float4 v = *reinterpret_cast<const float4*>(
          Bw + (size_t)(n0 + row) * ldb + k0 + kq * 4);
      Bs[kq * 4 + 0][row] = v.x;
      Bs[kq * 4 + 1][row] = v.y;
      Bs[kq * 4 + 2][row] = v.z;
      Bs[kq * 4 + 3][row] = v.w;
    }
    __syncthreads();
    #pragma unroll
    for (int k = 0; k < BK; ++k) {
      float a[TM], b[TN];
      #pragma unroll
      for (int i = 0; i < TM; ++i) a[i] = As[k][ty * TM + i];
      #pragma unroll
      for (int j = 0; j < TN; ++j) b[j] = Bs[k][tx * TN + j];
      #pragma unroll
      for (int i = 0; i < TM; ++i)
        #pragma unroll
        for (int j = 0; j < TN; ++j)
          acc[i][j] = fmaf(a[i], b[j], acc[i][j]);
    }
  }

  float* out = P + (size_t)blockIdx.z * M * N;
  #pragma unroll
  for (int i = 0; i < TM; ++i)
    #pragma unroll
    for (int j = 0; j < TN; ++j)
      out[(size_t)(m0 + ty * TM + i) * N + n0 + tx * TN + j] = acc[i][j];
}

__global__ __launch_bounds__(256)
void xproj_reduce(const float* __restrict__ part, float* __restrict__ xdbl) {
  const int i = (blockIdx.x * 256 + threadIdx.x) * 4;   // over 2048*96
  if (i >= MM * 96) return;
  float4 s = *reinterpret_cast<const float4*>(part + i);
  #pragma unroll
  for (int z = 1; z < 8; ++z) {
    const float4 v = *reinterpret_cast<const float4*>(part + (size_t)z * MM * 96 + i);
    s.x += v.x; s.y += v.y; s.z += v.z; s.w += v.w;
  }
  *reinterpret_cast<float4*>(xdbl + i) = s;
}

// ---------------------------------------------------------------------------
// Depthwise causal conv1d (k=4) + bias + SiLU.
// ---------------------------------------------------------------------------
__global__ __launch_bounds__(256)
void conv_silu(const float* __restrict__ xz, const float* __restrict__ cw,
               const float* __restrict__ cb, float* __restrict__ xc) {
  const int idx = blockIdx.x * 256 + threadIdx.x;
  if (idx >= MM * DINNER) return;
  const int d = idx & (DINNER - 1);
  const int m = idx >> 11;
  const int l = m & (LL - 1);
  const int b = m >> 10;
  float acc = cb[d];
  #pragma unroll
  for (int j = 0; j < DCONV; ++j) {
    const int ll = l - (DCONV - 1) + j;
    if (ll >= 0)
      acc = fmaf(xz[((size_t)(b * LL + ll) << 12) + d], cw[d * DCONV + j], acc);
  }
  xc[idx] = acc / (1.f + __expf(-acc));   // silu
}

// ---------------------------------------------------------------------------
// Chunked parallel selective scan (3 passes).
// ---------------------------------------------------------------------------
__device__ __forceinline__ void stage_tile(const float* g, int stride,
                                           float* ldst, int lane) {
  const int r  = lane >> 2;
  const int q4 = (lane & 3) * 4;
  #pragma unroll
  for (int i = 0; i < 4; ++i) {
    __builtin_amdgcn_global_load_lds(
        AS1(g + (size_t)(i * 16 + r) * stride + q4),
        AS3(ldst + i * 256), 16, 0, 0);
  }
}

__device__ __forceinline__ float quad_sum(float v) {
  int i = __float_as_int(v);
  v += __int_as_float(__builtin_amdgcn_update_dpp(0, i, 0xB1, 0xf, 0xf, true)); // xor 1
  i = __float_as_int(v);
  v += __int_as_float(__builtin_amdgcn_update_dpp(0, i, 0x4E, 0xf, 0xf, true)); // xor 2
  return v;
}

__global__ __launch_bounds__(64)
void scan_chunk_state(const float* __restrict__ delta, const float* __restrict__ xc,
                      const float* __restrict__ xdbl, const float* __restrict__ A_log,
                      float* __restrict__ hend, float* __restrict__ aprod) {
  __shared__ float dT[CL][16];
  __shared__ float xT[CL][16];
  __shared__ float bT[CL][16];

  const int idx = blockIdx.x;          // (b*128 + dg)*16 + c
  const int c  = idx & 15;
  const int dg = (idx >> 4) & 127;
  const int b  = idx >> 11;
  const int t  = threadIdx.x;
  const int ch = t >> 2;
  const int q  = t & 3;
  const int d  = dg * 16 + ch;

  const size_t r0 = (size_t)b * LL + (size_t)c * CL;
  stage_tile(delta + r0 * DINNER + dg * 16, DINNER, &dT[0][0], t);
  stage_tile(xc    + r0 * DINNER + dg * 16, DINNER, &xT[0][0], t);
  stage_tile(xdbl  + r0 * 96 + DTRANK,          96, &bT[0][0], t);

  float Adn[4];
  #pragma unroll
  for (int j = 0; j < 4; ++j)
    Adn[j] = -__expf(A_log[d * DSTATE + 4 * q + j]);
  float h0 = 0.f, h1 = 0.f, h2 = 0.f, h3 = 0.f;
  float p0 = 1.f, p1 = 1.f, p2 = 1.f, p3 = 1.f;

  __syncthreads();

  #pragma unroll 8
  for (int l = 0; l < CL; ++l) {
    const float dv = dT[l][ch];
    const float xv = xT[l][ch];
    const float4 B4 = *reinterpret_cast<const float4*>(&bT[l][4 * q]);
    const float dvx = dv * xv;
    const float a0 = __expf(dv * Adn[0]);
    const float a1 = __expf(dv * Adn[1]);
    const float a2 = __expf(dv * Adn[2]);
    const float a3 = __expf(dv * Adn[3]);
    h0 = fmaf(a0, h0, dvx * B4.x);  p0 *= a0;
    h1 = fmaf(a1, h1, dvx * B4.y);  p1 *= a1;
    h2 = fmaf(a2, h2, dvx * B4.z);  p2 *= a2;
    h3 = fmaf(a3, h3, dvx * B4.w);  p3 *= a3;
  }

  const size_t base = (((size_t)(b * NCH + c) * DINNER) + d) * DSTATE + 4 * q;
  *reinterpret_cast<float4*>(hend  + base) = (float4){h0, h1, h2, h3};
  *reinterpret_cast<float4*>(aprod + base) = (float4){p0, p1, p2, p3};
}

__global__ __launch_bounds__(256)
void scan_combine(const float* __restrict__ hend, const float* __restrict__ aprod,
                  float* __restrict__ hin) {
  const int tid = blockIdx.x * 256 + threadIdx.x;   // 65536 total
  const size_t cstride = (size_t)DINNER * DSTATE;   // 32768
  const size_t base = (size_t)(tid >> 15) * NCH * cstride + (tid & 32767);
  float h = 0.f;
  hin[base] = 0.f;
  #pragma unroll
  for (int c = 0; c < NCH - 1; ++c) {
    h = fmaf(aprod[base + (size_t)c * cstride], h, hend[base + (size_t)c * cstride]);
    hin[base + (size_t)(c + 1) * cstride] = h;
  }
}

__global__ __launch_bounds__(64)
void scan_apply(const float* __restrict__ delta, const float* __restrict__ xc,
                const float* __restrict__ xdbl, const float* __restrict__ xz,
                const float* __restrict__ A_log, const float* __restrict__ Dp,
                const float* __restrict__ hin,
                ushort* __restrict__ yh, ushort* __restrict__ yl) {
  __shared__ float dT[CL][16];
  __shared__ float xT[CL][16];
  __shared__ float bT[CL][16];
  __shared__ float cT[CL][16];
  __shared__ float zT[CL][16];

  const int idx = blockIdx.x;
  const int c  = idx & 15;
  const int dg = (idx >> 4) & 127;
  const int b  = idx >> 11;
  const int t  = threadIdx.x;
  const int ch = t >> 2;
  const int q  = t & 3;
  const int d  = dg * 16 + ch;

  const size_t r0 = (size_t)b * LL + (size_t)c * CL;
  stage_tile(delta + r0 * DINNER + dg * 16, DINNER, &dT[0][0], t);
  stage_tile(xc    + r0 * DINNER + dg * 16, DINNER, &xT[0][0], t);
  stage_tile(xdbl  + r0 * 96 + DTRANK,          96, &bT[0][0], t);
  stage_tile(xdbl  + r0 * 96 + DTRANK + DSTATE, 96, &cT[0][0], t);
  stage_tile(xz    + (r0 << 12) + DINNER + dg * 16, 4096, &zT[0][0], t);

  float Adn[4];
  #pragma unroll
  for (int j = 0; j < 4; ++j)
    Adn[j] = -__expf(A_log[d * DSTATE + 4 * q + j]);
  const float Dd = Dp[d];

  const size_t base = (((size_t)(b * NCH + c) * DINNER) + d) * DSTATE + 4 * q;
  const float4 h4 = *reinterpret_cast<const float4*>(hin + base);
  float h0 = h4.x, h1 = h4.y, h2 = h4.z, h3 = h4.w;

  __syncthreads();

  #pragma unroll 8
  for (int l = 0; l < CL; ++l) {
    const float dv = dT[l][ch];
    const float xv = xT[l][ch];
    const float4 B4 = *reinterpret_cast<const float4*>(&bT[l][4 * q]);
    const float4 C4 = *reinterpret_cast<const float4*>(&cT[l][4 * q]);
    const float dvx = dv * xv;
    const float a0 = __expf(dv * Adn[0]);
    const float a1 = __expf(dv * Adn[1]);
    const float a2 = __expf(dv * Adn[2]);
    const float a3 = __expf(dv * Adn[3]);
    h0 = fmaf(a0, h0, dvx * B4.x);
    h1 = fmaf(a1, h1, dvx * B4.y);
    h2 = fmaf(a2, h2, dvx * B4.z);
    h3 = fmaf(a3, h3, dvx * B4.w);
    float ys = fmaf(h0, C4.x, fmaf(h1, C4.y, fmaf(h2, C4.z, h3 * C4.w)));
    ys = quad_sum(ys);
    if (q == 0) {
      const float zv = zT[l][ch];
      const float g  = zv / (1.f + __expf(-zv));
      const float tv = (ys + xv * Dd) * g;
      const size_t oidx = (r0 + l) * (size_t)DINNER + d;
      const ushort hh = bf16_rne(tv);
      yh[oidx] = hh;
      yl[oidx] = bf16_rne(tv - __uint_as_float((uint)hh << 16));
    }
  }
}

// ---------------------------------------------------------------------------
extern "C" void kernel_launch(void* const* d_in, const int* in_sizes, int n_in,
                              void* d_out, int out_size, void* d_ws, size_t ws_size,
                              hipStream_t stream) {
  const float* x         = (const float*)d_in[0];
  const float* in_proj_w = (const float*)d_in[1];
  const float* conv_w    = (const float*)d_in[2];
  const float* conv_b    = (const float*)d_in[3];
  const float* x_proj_w  = (const float*)d_in[4];
  const float* dt_proj_w = (const float*)d_in[5];
  const float* dt_proj_b = (const float*)d_in[6];
  const float* A_log     = (const float*)d_in[7];
  const float* Dv        = (const float*)d_in[8];
  const float* out_proj_w= (const float*)d_in[9];
  float* out = (float*)d_out;

  float* ws    = (float*)d_ws;
  float* xz    = ws;                          // [2048][4096] f32
  float* xc    = xz    + (size_t)MM * 4096;   // [2048][2048] f32
  float* xdbl  = xc    + (size_t)MM * DINNER; // [2048][96]   f32
  float* delta = xdbl  + (size_t)MM * 96;     // [2048][2048] f32
  ushort* us   = (ushort*)(delta + (size_t)MM * DINNER);
  ushort* yhp  = us;                           // [2048][2048] bf16 hi
  ushort* ylp  = yhp + (size_t)MM * DINNER;    // [2048][2048] bf16 lo
  ushort* xh   = ylp + (size_t)MM * DINNER;    // [2048][1024]
  ushort* xl   = xh  + (size_t)MM * DMODEL;
  ushort* wih  = xl  + (size_t)MM * DMODEL;    // [4096][1024]
  ushort* wil  = wih + (size_t)4096 * DMODEL;
  ushort* woh  = wil + (size_t)4096 * DMODEL;  // [1024][2048]
  ushort* wol  = woh + (size_t)DMODEL * DINNER;

  // aliases onto dead regions:
  // hend/aprod/hin (scan) live in wih/wil (dead after in_proj GEMM)
  float* hend  = (float*)wih;
  float* aprod = hend  + (size_t)BB * NCH * DINNER * DSTATE;
  float* hin   = aprod + (size_t)BB * NCH * DINNER * DSTATE;
  // x_proj split-K partials [8][2048][96] = 6.3 MB (consumed before scan)
  float* part  = hend;
  // out_proj split-K partials [2][2048][1024] f32 = 16.8 MB (after scan,
  // exactly fills the wih+wil region)
  float* opart = hend;
  // dt hi/lo + dt_proj_w hi/lo live in xh/xl (dead after in_proj GEMM)
  ushort* dth = xh;            ushort* dtl = xl;
  ushort* wdh = xh + 131072;   ushort* wdl = xl + 131072;

  const dim3 blk(256);

  // 0) precision splits (x, weights)
  split_hl<<<dim3((MM * DMODEL) / 1024), blk, 0, stream>>>(x, xh, xl, MM * DMODEL);
  split_hl<<<dim3((4096 * DMODEL) / 1024), blk, 0, stream>>>(in_proj_w, wih, wil, 4096 * DMODEL);
  split_hl<<<dim3((DMODEL * DINNER) / 1024), blk, 0, stream>>>(out_proj_w, woh, wol, DMODEL * DINNER);

  // 1) in_proj (MFMA split-bf16, pipelined): xz = x @ in_proj_w^T
  gemm_hl_mfma<0,1><<<dim3(4096 / 128, MM / 128), blk, 0, stream>>>(
      xh, xl, wih, wil, xz, nullptr, MM, 4096, DMODEL);

  // 2) causal depthwise conv + silu -> xc
  conv_silu<<<dim3((MM * DINNER) / 256), blk, 0, stream>>>(xz, conv_w, conv_b, xc);

  // 3) x_proj split-K: xdbl = xc @ x_proj_w^T  (M=2048, N=96, K=2048)
  gemm_nt_part<64,32,4,2,256><<<dim3(96/32, MM/64, 8), blk, 0, stream>>>(
      xc, x_proj_w, part, MM, 96, DINNER, DINNER);
  xproj_reduce<<<dim3((MM * 96) / 1024), blk, 0, stream>>>(part, xdbl);

  // 4) dt_proj (MFMA split-bf16 + softplus): delta = sp(dt @ dt_proj_w^T + b)
  split_hl<<<dim3((DINNER * DTRANK) / 1024), blk, 0, stream>>>(
      dt_proj_w, wdh, wdl, DINNER * DTRANK);
  split_dt<<<dim3((MM * 16) / 256), blk, 0, stream>>>(xdbl, dth, dtl);
  gemm_hl_mfma<1,1><<<dim3(DINNER / 128, MM / 128), blk, 0, stream>>>(
      dth, dtl, wdh, wdl, delta, dt_proj_b, MM, DINNER, DTRANK);

  // 5) chunked parallel scan (A: local states, B: combine, C: apply+epilogue)
  scan_chunk_state<<<dim3(BB * 128 * NCH), dim3(64), 0, stream>>>(
      delta, xc, xdbl, A_log, hend, aprod);
  scan_combine<<<dim3(BB * DINNER * DSTATE / 256), blk, 0, stream>>>(
      hend, aprod, hin);
  scan_apply<<<dim3(BB * 128 * NCH), dim3(64), 0, stream>>>(
      delta, xc, xdbl, xz, A_log, Dv, hin, yhp, ylp);

  // 6) out_proj (MFMA split-bf16, split-K=2): out = y @ out_proj_w^T
  gemm_hl_mfma<0,2><<<dim3(DMODEL / 128, MM / 128, 2), blk, 0, stream>>>(
      yhp, ylp, woh, wol, opart, nullptr, MM, DMODEL, DINNER);
  splitk_reduce<<<dim3((MM * DMODEL) / 1024), blk, 0, stream>>>(
      opart, out, MM * DMODEL);
}

// Round 7
// 199.639 us; speedup vs baseline: 6.7493x; 1.1486x over previous
//
#include <hip/hip_runtime.h>
#include <math.h>
#include <stdint.h>

#define DMODEL 1024
#define DINNER 2048
#define DCONV  4
#define DSTATE 16
#define DTRANK 64
#define BB 2
#define LL 1024
#define MM (BB * LL)            // 2048 rows in all GEMMs

#define CL  64                  // scan chunk length
#define NCH (LL / CL)           // 16 chunks

#define AS1(p) ((__attribute__((address_space(1))) void*)(void*)(p))
#define AS3(p) ((__attribute__((address_space(3))) void*)(void*)(p))

typedef __attribute__((ext_vector_type(8))) short bf16x8;
typedef __attribute__((ext_vector_type(4))) float f32x4;

__device__ __forceinline__ ushort bf16_rne(float f) {
  uint32_t u = __float_as_uint(f);
  uint32_t r = (u + 0x7fffu + ((u >> 16) & 1u)) >> 16;
  return (ushort)r;
}

// ---------------------------------------------------------------------------
// Fused f32 -> (hi, lo) bf16 split for 4 arrays in one launch.
// Sizes in float4 units; each thread handles one float4.
// ---------------------------------------------------------------------------
__device__ __forceinline__ void split4(const float* __restrict__ in,
                                       ushort* __restrict__ hi,
                                       ushort* __restrict__ lo, int i4) {
  const float4 v = *reinterpret_cast<const float4*>(in + (size_t)i4 * 4);
  ushort4 h, l;
  h.x = bf16_rne(v.x); l.x = bf16_rne(v.x - __uint_as_float((uint)h.x << 16));
  h.y = bf16_rne(v.y); l.y = bf16_rne(v.y - __uint_as_float((uint)h.y << 16));
  h.z = bf16_rne(v.z); l.z = bf16_rne(v.z - __uint_as_float((uint)h.z << 16));
  h.w = bf16_rne(v.w); l.w = bf16_rne(v.w - __uint_as_float((uint)h.w << 16));
  *reinterpret_cast<ushort4*>(hi + (size_t)i4 * 4) = h;
  *reinterpret_cast<ushort4*>(lo + (size_t)i4 * 4) = l;
}

__global__ __launch_bounds__(256)
void split3(const float* s0, ushort* h0, ushort* l0, int n0,
            const float* s1, ushort* h1, ushort* l1, int n1,
            const float* s2, ushort* h2, ushort* l2, int n2,
            const float* s3, ushort* h3, ushort* l3, int n3) {
  int i = blockIdx.x * 256 + threadIdx.x;
  if (i < n0) { split4(s0, h0, l0, i); return; }
  i -= n0;
  if (i < n1) { split4(s1, h1, l1, i); return; }
  i -= n1;
  if (i < n2) { split4(s2, h2, l2, i); return; }
  i -= n2;
  if (i < n3) { split4(s3, h3, l3, i); return; }
}

// ---------------------------------------------------------------------------
// Split-precision bf16 MFMA NT GEMM (3-product), 2-phase double-buffered.
// EPI 0: C=acc.  EPI 1: C=softplus(acc+bias[n]).
// ---------------------------------------------------------------------------
__device__ __forceinline__ int swz4(int r) { return (r & 3) ^ ((r >> 2) & 3); }

template<int EPI, int SPLITK>
__global__ __launch_bounds__(256)
void gemm_hl_mfma(const ushort* __restrict__ Ahg, const ushort* __restrict__ Alg,
                  const ushort* __restrict__ Bhg, const ushort* __restrict__ Blg,
                  float* __restrict__ C, const float* __restrict__ bias,
                  int M, int N, int K) {
  __shared__ ushort Ah[2][128][32];
  __shared__ ushort Al[2][128][32];
  __shared__ ushort Bh[2][128][32];
  __shared__ ushort Bl[2][128][32];

  const int tid  = threadIdx.x;
  const int wave = tid >> 6;
  const int lane = tid & 63;
  const int m0 = blockIdx.y * 128;
  const int n0 = blockIdx.x * 128;
  const int wm = (wave >> 1) * 64;
  const int wn = (wave & 1) * 64;

  const int ksl = K / SPLITK;
  const int kb  = blockIdx.z * ksl;
  float* Cout   = C + (size_t)blockIdx.z * M * N;

  f32x4 acc[4][4];
  #pragma unroll
  for (int i = 0; i < 4; ++i)
    #pragma unroll
    for (int j = 0; j < 4; ++j)
      acc[i][j] = (f32x4){0.f, 0.f, 0.f, 0.f};

  const ushort* gsrc; ushort* dst; int row0;
  if      (wave == 0) { gsrc = Ahg; dst = &Ah[0][0][0]; row0 = m0; }
  else if (wave == 1) { gsrc = Alg; dst = &Al[0][0][0]; row0 = m0; }
  else if (wave == 2) { gsrc = Bhg; dst = &Bh[0][0][0]; row0 = n0; }
  else                { gsrc = Blg; dst = &Bl[0][0][0]; row0 = n0; }

  const int lr = lane >> 2;
  const int ls = lane & 3;
  const int fr = lane & 15;
  const int q  = lane >> 4;

  auto STAGE = [&](int bi, int k0) {
    ushort* d = dst + bi * 4096;
    #pragma unroll
    for (int seg = 0; seg < 8; ++seg) {
      const int rho = seg * 16 + lr;
      const int ks  = (ls ^ swz4(rho)) * 8;
      __builtin_amdgcn_global_load_lds(
          AS1(gsrc + (size_t)(row0 + rho) * K + k0 + ks),
          AS3(d + seg * 512), 16, 0, 0);
    }
  };

  const int NT = ksl / 32;
  STAGE(0, kb);
  __syncthreads();

  int cur = 0;
  for (int kt = 0; kt < NT; ++kt) {
    if (kt + 1 < NT) STAGE(cur ^ 1, kb + (kt + 1) * 32);

    bf16x8 ah[4], al[4], bh[4], bl[4];
    #pragma unroll
    for (int f = 0; f < 4; ++f) {
      { const int r = wm + f * 16 + fr; const int s = 8 * (q ^ swz4(r));
        ah[f] = *reinterpret_cast<const bf16x8*>(&Ah[cur][r][s]);
        al[f] = *reinterpret_cast<const bf16x8*>(&Al[cur][r][s]); }
      { const int r = wn + f * 16 + fr; const int s = 8 * (q ^ swz4(r));
        bh[f] = *reinterpret_cast<const bf16x8*>(&Bh[cur][r][s]);
        bl[f] = *reinterpret_cast<const bf16x8*>(&Bl[cur][r][s]); }
    }
    #pragma unroll
    for (int i = 0; i < 4; ++i)
      #pragma unroll
      for (int j = 0; j < 4; ++j) {
        acc[i][j] = __builtin_amdgcn_mfma_f32_16x16x32_bf16(ah[i], bh[j], acc[i][j], 0, 0, 0);
        acc[i][j] = __builtin_amdgcn_mfma_f32_16x16x32_bf16(al[i], bh[j], acc[i][j], 0, 0, 0);
        acc[i][j] = __builtin_amdgcn_mfma_f32_16x16x32_bf16(ah[i], bl[j], acc[i][j], 0, 0, 0);
      }

    __syncthreads();
    cur ^= 1;
  }

  const int cr = (lane >> 4) * 4;
  const int cc = lane & 15;
  #pragma unroll
  for (int i = 0; i < 4; ++i)
    #pragma unroll
    for (int j = 0; j < 4; ++j) {
      const int cn = n0 + wn + j * 16 + cc;
      const float bj = (EPI == 1) ? bias[cn] : 0.f;
      const size_t base = (size_t)(m0 + wm + i * 16 + cr) * N + cn;
      #pragma unroll
      for (int r = 0; r < 4; ++r) {
        float v = acc[i][j][r];
        if (EPI == 1) {
          v += bj;
          v = fmaxf(v, 0.f) + __logf(1.f + __expf(-fabsf(v)));   // softplus
        }
        Cout[base + (size_t)r * N] = v;
      }
    }
}

// ---------------------------------------------------------------------------
// 2-product MFMA NT GEMM (out_proj): C = Ah @ (Bh+Bl)^T, 3 staged planes,
// 48 KB LDS, split-K via blockIdx.z.
// ---------------------------------------------------------------------------
template<int SPLITK>
__global__ __launch_bounds__(256)
void gemm_p2_mfma(const ushort* __restrict__ Ahg, const ushort* __restrict__ Bhg,
                  const ushort* __restrict__ Blg, float* __restrict__ P,
                  int M, int N, int K) {
  __shared__ ushort Ah[2][128][32];
  __shared__ ushort Bh[2][128][32];
  __shared__ ushort Bl[2][128][32];

  const int tid  = threadIdx.x;
  const int wave = tid >> 6;
  const int lane = tid & 63;
  const int m0 = blockIdx.y * 128;
  const int n0 = blockIdx.x * 128;
  const int wm = (wave >> 1) * 64;
  const int wn = (wave & 1) * 64;

  const int ksl = K / SPLITK;
  const int kb  = blockIdx.z * ksl;
  float* Cout   = P + (size_t)blockIdx.z * M * N;

  f32x4 acc[4][4];
  #pragma unroll
  for (int i = 0; i < 4; ++i)
    #pragma unroll
    for (int j = 0; j < 4; ++j)
      acc[i][j] = (f32x4){0.f, 0.f, 0.f, 0.f};

  const ushort* gsrc = nullptr; ushort* dst = nullptr; int row0 = 0;
  if      (wave == 0) { gsrc = Ahg; dst = &Ah[0][0][0]; row0 = m0; }
  else if (wave == 1) { gsrc = Bhg; dst = &Bh[0][0][0]; row0 = n0; }
  else if (wave == 2) { gsrc = Blg; dst = &Bl[0][0][0]; row0 = n0; }

  const int lr = lane >> 2;
  const int ls = lane & 3;
  const int fr = lane & 15;
  const int q  = lane >> 4;

  auto STAGE = [&](int bi, int k0) {
    if (wave >= 3) return;
    ushort* d = dst + bi * 4096;
    #pragma unroll
    for (int seg = 0; seg < 8; ++seg) {
      const int rho = seg * 16 + lr;
      const int ks  = (ls ^ swz4(rho)) * 8;
      __builtin_amdgcn_global_load_lds(
          AS1(gsrc + (size_t)(row0 + rho) * K + k0 + ks),
          AS3(d + seg * 512), 16, 0, 0);
    }
  };

  const int NT = ksl / 32;
  STAGE(0, kb);
  __syncthreads();

  int cur = 0;
  for (int kt = 0; kt < NT; ++kt) {
    if (kt + 1 < NT) STAGE(cur ^ 1, kb + (kt + 1) * 32);

    bf16x8 ah[4], bh[4], bl[4];
    #pragma unroll
    for (int f = 0; f < 4; ++f) {
      { const int r = wm + f * 16 + fr; const int s = 8 * (q ^ swz4(r));
        ah[f] = *reinterpret_cast<const bf16x8*>(&Ah[cur][r][s]); }
      { const int r = wn + f * 16 + fr; const int s = 8 * (q ^ swz4(r));
        bh[f] = *reinterpret_cast<const bf16x8*>(&Bh[cur][r][s]);
        bl[f] = *reinterpret_cast<const bf16x8*>(&Bl[cur][r][s]); }
    }
    #pragma unroll
    for (int i = 0; i < 4; ++i)
      #pragma unroll
      for (int j = 0; j < 4; ++j) {
        acc[i][j] = __builtin_amdgcn_mfma_f32_16x16x32_bf16(ah[i], bh[j], acc[i][j], 0, 0, 0);
        acc[i][j] = __builtin_amdgcn_mfma_f32_16x16x32_bf16(ah[i], bl[j], acc[i][j], 0, 0, 0);
      }

    __syncthreads();
    cur ^= 1;
  }

  const int cr = (lane >> 4) * 4;
  const int cc = lane & 15;
  #pragma unroll
  for (int i = 0; i < 4; ++i)
    #pragma unroll
    for (int j = 0; j < 4; ++j) {
      const size_t base = (size_t)(m0 + wm + i * 16 + cr) * N + (n0 + wn + j * 16 + cc);
      #pragma unroll
      for (int r = 0; r < 4; ++r)
        Cout[base + (size_t)r * N] = acc[i][j][r];
    }
}

// sum 4 split-K partial planes -> out
__global__ __launch_bounds__(256)
void splitk_reduce4(const float* __restrict__ P, float* __restrict__ out, int n) {
  const int i = (blockIdx.x * 256 + threadIdx.x) * 4;
  if (i >= n) return;
  float4 s = *reinterpret_cast<const float4*>(P + i);
  #pragma unroll
  for (int z = 1; z < 4; ++z) {
    const float4 v = *reinterpret_cast<const float4*>(P + (size_t)z * n + i);
    s.x += v.x; s.y += v.y; s.z += v.z; s.w += v.w;
  }
  *reinterpret_cast<float4*>(out + i) = s;
}

// ---------------------------------------------------------------------------
// Split-K f32 NT GEMM partials (x_proj)
// ---------------------------------------------------------------------------
template<int BM, int BN, int TM, int TN, int KSLICE>
__global__ __launch_bounds__(256)
void gemm_nt_part(const float* __restrict__ A, const float* __restrict__ Bw,
                  float* __restrict__ P, int M, int N, int lda, int ldb) {
  constexpr int BK  = 16;
  constexpr int NTX = BN / TN;
  constexpr int NTY = BM / TM;
  static_assert(NTX * NTY == 256, "thread tile mismatch");
  __shared__ float As[BK][BM + 4];
  __shared__ float Bs[BK][BN + 4];

  const int tid = threadIdx.x;
  const int m0  = blockIdx.y * BM;
  const int n0  = blockIdx.x * BN;
  const int kb  = blockIdx.z * KSLICE;
  const int tx  = tid % NTX;
  const int ty  = tid / NTX;

  float acc[TM][TN] = {};

  for (int k0 = kb; k0 < kb + KSLICE; k0 += BK) {
    __syncthreads();
    for (int t = tid; t < BM * 4; t += 256) {
      const int row = t >> 2, kq = t & 3;
      const float4 v = *reinterpret_cast<const float4*>(
          A + (size_t)(m0 + row) * lda + k0 + kq * 4);
      As[kq * 4 + 0][row] = v.x;
      As[kq * 4 + 1][row] = v.y;
      As[kq * 4 + 2][row] = v.z;
      As[kq * 4 + 3][row] = v.w;
    }
    for (int t = tid; t < BN * 4; t += 256) {
      const int row = t >> 2, kq = t & 3;
      const float4 v = *reinterpret_cast<const float4*>(
          Bw + (size_t)(n0 + row) * ldb + k0 + kq * 4);
      Bs[kq * 4 + 0][row] = v.x;
      Bs[kq * 4 + 1][row] = v.y;
      Bs[kq * 4 + 2][row] = v.z;
      Bs[kq * 4 + 3][row] = v.w;
    }
    __syncthreads();
    #pragma unroll
    for (int k = 0; k < BK; ++k) {
      float a[TM], b[TN];
      #pragma unroll
      for (int i = 0; i < TM; ++i) a[i] = As[k][ty * TM + i];
      #pragma unroll
      for (int j = 0; j < TN; ++j) b[j] = Bs[k][tx * TN + j];
      #pragma unroll
      for (int i = 0; i < TM; ++i)
        #pragma unroll
        for (int j = 0; j < TN; ++j)
          acc[i][j] = fmaf(a[i], b[j], acc[i][j]);
    }
  }

  float* out = P + (size_t)blockIdx.z * M * N;
  #pragma unroll
  for (int i = 0; i < TM; ++i)
    #pragma unroll
    for (int j = 0; j < TN; ++j)
      out[(size_t)(m0 + ty * TM + i) * N + n0 + tx * TN + j] = acc[i][j];
}

// reduce x_proj partials; dt cols (0..63) -> packed bf16 hi/lo, B/C cols -> f32
__global__ __launch_bounds__(256)
void xpr_fused(const float* __restrict__ part, float* __restrict__ xdbl,
               ushort* __restrict__ dth, ushort* __restrict__ dtl) {
  const int i = blockIdx.x * 256 + threadIdx.x;   // float4 over [2048][24]
  if (i >= MM * 24) return;
  const int m  = i / 24;
  const int c4 = (i % 24) * 4;
  const size_t off = (size_t)m * 96 + c4;
  float4 s = *reinterpret_cast<const float4*>(part + off);
  #pragma unroll
  for (int z = 1; z < 8; ++z) {
    const float4 v = *reinterpret_cast<const float4*>(part + (size_t)z * MM * 96 + off);
    s.x += v.x; s.y += v.y; s.z += v.z; s.w += v.w;
  }
  if (c4 < 64) {
    ushort4 h, l;
    h.x = bf16_rne(s.x); l.x = bf16_rne(s.x - __uint_as_float((uint)h.x << 16));
    h.y = bf16_rne(s.y); l.y = bf16_rne(s.y - __uint_as_float((uint)h.y << 16));
    h.z = bf16_rne(s.z); l.z = bf16_rne(s.z - __uint_as_float((uint)h.z << 16));
    h.w = bf16_rne(s.w); l.w = bf16_rne(s.w - __uint_as_float((uint)h.w << 16));
    *reinterpret_cast<ushort4*>(dth + (size_t)m * 64 + c4) = h;
    *reinterpret_cast<ushort4*>(dtl + (size_t)m * 64 + c4) = l;
  } else {
    *reinterpret_cast<float4*>(xdbl + off) = s;
  }
}

// ---------------------------------------------------------------------------
// Depthwise causal conv1d (k=4) + bias + SiLU, float4-vectorized.
// ---------------------------------------------------------------------------
__global__ __launch_bounds__(256)
void conv_silu(const float* __restrict__ xz, const float* __restrict__ cw,
               const float* __restrict__ cb, float* __restrict__ xc) {
  const int idx = blockIdx.x * 256 + threadIdx.x;   // over MM*DINNER/4
  if (idx >= MM * DINNER / 4) return;
  const int d4 = (idx & 511) * 4;       // DINNER/4 = 512 per row
  const int m  = idx >> 9;
  const int l  = m & (LL - 1);
  const int b  = m >> 10;

  float4 w0 = *reinterpret_cast<const float4*>(cw + (size_t)(d4 + 0) * 4);
  float4 w1 = *reinterpret_cast<const float4*>(cw + (size_t)(d4 + 1) * 4);
  float4 w2 = *reinterpret_cast<const float4*>(cw + (size_t)(d4 + 2) * 4);
  float4 w3 = *reinterpret_cast<const float4*>(cw + (size_t)(d4 + 3) * 4);
  float4 acc = *reinterpret_cast<const float4*>(cb + d4);

  #pragma unroll
  for (int j = 0; j < DCONV; ++j) {
    const int ll = l - (DCONV - 1) + j;
    if (ll >= 0) {
      const float4 xv = *reinterpret_cast<const float4*>(
          xz + ((size_t)(b * LL + ll) << 12) + d4);
      acc.x = fmaf(xv.x, (&w0.x)[j], acc.x);
      acc.y = fmaf(xv.y, (&w1.x)[j], acc.y);
      acc.z = fmaf(xv.z, (&w2.x)[j], acc.z);
      acc.w = fmaf(xv.w, (&w3.x)[j], acc.w);
    }
  }
  float4 o;
  o.x = acc.x / (1.f + __expf(-acc.x));
  o.y = acc.y / (1.f + __expf(-acc.y));
  o.z = acc.z / (1.f + __expf(-acc.z));
  o.w = acc.w / (1.f + __expf(-acc.w));
  *reinterpret_cast<float4*>(xc + (size_t)m * DINNER + d4) = o;
}

// ---------------------------------------------------------------------------
// Chunked parallel selective scan (3 passes).
// ---------------------------------------------------------------------------
__device__ __forceinline__ void stage_tile(const float* g, int stride,
                                           float* ldst, int lane) {
  const int r  = lane >> 2;
  const int q4 = (lane & 3) * 4;
  #pragma unroll
  for (int i = 0; i < 4; ++i) {
    __builtin_amdgcn_global_load_lds(
        AS1(g + (size_t)(i * 16 + r) * stride + q4),
        AS3(ldst + i * 256), 16, 0, 0);
  }
}

__device__ __forceinline__ float quad_sum(float v) {
  int i = __float_as_int(v);
  v += __int_as_float(__builtin_amdgcn_update_dpp(0, i, 0xB1, 0xf, 0xf, true)); // xor 1
  i = __float_as_int(v);
  v += __int_as_float(__builtin_amdgcn_update_dpp(0, i, 0x4E, 0xf, 0xf, true)); // xor 2
  return v;
}

__global__ __launch_bounds__(64)
void scan_chunk_state(const float* __restrict__ delta, const float* __restrict__ xc,
                      const float* __restrict__ xdbl, const float* __restrict__ A_log,
                      float* __restrict__ hend, float* __restrict__ aprod) {
  __shared__ float dT[CL][16];
  __shared__ float xT[CL][16];
  __shared__ float bT[CL][16];

  const int idx = blockIdx.x;          // (b*128 + dg)*16 + c
  const int c  = idx & 15;
  const int dg = (idx >> 4) & 127;
  const int b  = idx >> 11;
  const int t  = threadIdx.x;
  const int ch = t >> 2;
  const int q  = t & 3;
  const int d  = dg * 16 + ch;

  const size_t r0 = (size_t)b * LL + (size_t)c * CL;
  stage_tile(delta + r0 * DINNER + dg * 16, DINNER, &dT[0][0], t);
  stage_tile(xc    + r0 * DINNER + dg * 16, DINNER, &xT[0][0], t);
  stage_tile(xdbl  + r0 * 96 + DTRANK,          96, &bT[0][0], t);

  float Adn[4];
  #pragma unroll
  for (int j = 0; j < 4; ++j)
    Adn[j] = -__expf(A_log[d * DSTATE + 4 * q + j]);
  float h0 = 0.f, h1 = 0.f, h2 = 0.f, h3 = 0.f;
  float p0 = 1.f, p1 = 1.f, p2 = 1.f, p3 = 1.f;

  __syncthreads();

  #pragma unroll 8
  for (int l = 0; l < CL; ++l) {
    const float dv = dT[l][ch];
    const float xv = xT[l][ch];
    const float4 B4 = *reinterpret_cast<const float4*>(&bT[l][4 * q]);
    const float dvx = dv * xv;
    const float a0 = __expf(dv * Adn[0]);
    const float a1 = __expf(dv * Adn[1]);
    const float a2 = __expf(dv * Adn[2]);
    const float a3 = __expf(dv * Adn[3]);
    h0 = fmaf(a0, h0, dvx * B4.x);  p0 *= a0;
    h1 = fmaf(a1, h1, dvx * B4.y);  p1 *= a1;
    h2 = fmaf(a2, h2, dvx * B4.z);  p2 *= a2;
    h3 = fmaf(a3, h3, dvx * B4.w);  p3 *= a3;
  }

  const size_t base = (((size_t)(b * NCH + c) * DINNER) + d) * DSTATE + 4 * q;
  *reinterpret_cast<float4*>(hend  + base) = (float4){h0, h1, h2, h3};
  *reinterpret_cast<float4*>(aprod + base) = (float4){p0, p1, p2, p3};
}

__global__ __launch_bounds__(256)
void scan_combine(const float* __restrict__ hend, const float* __restrict__ aprod,
                  float* __restrict__ hin) {
  const int tid = blockIdx.x * 256 + threadIdx.x;   // 65536 total
  const size_t cstride = (size_t)DINNER * DSTATE;   // 32768
  const size_t base = (size_t)(tid >> 15) * NCH * cstride + (tid & 32767);
  float h = 0.f;
  hin[base] = 0.f;
  #pragma unroll
  for (int c = 0; c < NCH - 1; ++c) {
    h = fmaf(aprod[base + (size_t)c * cstride], h, hend[base + (size_t)c * cstride]);
    hin[base + (size_t)(c + 1) * cstride] = h;
  }
}

__global__ __launch_bounds__(64)
void scan_apply(const float* __restrict__ delta, const float* __restrict__ xc,
                const float* __restrict__ xdbl, const float* __restrict__ xz,
                const float* __restrict__ A_log, const float* __restrict__ Dp,
                const float* __restrict__ hin, ushort* __restrict__ yh) {
  __shared__ float dT[CL][16];
  __shared__ float xT[CL][16];
  __shared__ float bT[CL][16];
  __shared__ float cT[CL][16];
  __shared__ float zT[CL][16];

  const int idx = blockIdx.x;
  const int c  = idx & 15;
  const int dg = (idx >> 4) & 127;
  const int b  = idx >> 11;
  const int t  = threadIdx.x;
  const int ch = t >> 2;
  const int q  = t & 3;
  const int d  = dg * 16 + ch;

  const size_t r0 = (size_t)b * LL + (size_t)c * CL;
  stage_tile(delta + r0 * DINNER + dg * 16, DINNER, &dT[0][0], t);
  stage_tile(xc    + r0 * DINNER + dg * 16, DINNER, &xT[0][0], t);
  stage_tile(xdbl  + r0 * 96 + DTRANK,          96, &bT[0][0], t);
  stage_tile(xdbl  + r0 * 96 + DTRANK + DSTATE, 96, &cT[0][0], t);
  stage_tile(xz    + (r0 << 12) + DINNER + dg * 16, 4096, &zT[0][0], t);

  float Adn[4];
  #pragma unroll
  for (int j = 0; j < 4; ++j)
    Adn[j] = -__expf(A_log[d * DSTATE + 4 * q + j]);
  const float Dd = Dp[d];

  const size_t base = (((size_t)(b * NCH + c) * DINNER) + d) * DSTATE + 4 * q;
  const float4 h4 = *reinterpret_cast<const float4*>(hin + base);
  float h0 = h4.x, h1 = h4.y, h2 = h4.z, h3 = h4.w;

  __syncthreads();

  #pragma unroll 8
  for (int l = 0; l < CL; ++l) {
    const float dv = dT[l][ch];
    const float xv = xT[l][ch];
    const float4 B4 = *reinterpret_cast<const float4*>(&bT[l][4 * q]);
    const float4 C4 = *reinterpret_cast<const float4*>(&cT[l][4 * q]);
    const float dvx = dv * xv;
    const float a0 = __expf(dv * Adn[0]);
    const float a1 = __expf(dv * Adn[1]);
    const float a2 = __expf(dv * Adn[2]);
    const float a3 = __expf(dv * Adn[3]);
    h0 = fmaf(a0, h0, dvx * B4.x);
    h1 = fmaf(a1, h1, dvx * B4.y);
    h2 = fmaf(a2, h2, dvx * B4.z);
    h3 = fmaf(a3, h3, dvx * B4.w);
    float ys = fmaf(h0, C4.x, fmaf(h1, C4.y, fmaf(h2, C4.z, h3 * C4.w)));
    ys = quad_sum(ys);
    if (q == 0) {
      const float zv = zT[l][ch];
      const float g  = zv / (1.f + __expf(-zv));
      const float tv = (ys + xv * Dd) * g;
      yh[(r0 + l) * (size_t)DINNER + d] = bf16_rne(tv);
    }
  }
}

// ---------------------------------------------------------------------------
extern "C" void kernel_launch(void* const* d_in, const int* in_sizes, int n_in,
                              void* d_out, int out_size, void* d_ws, size_t ws_size,
                              hipStream_t stream) {
  const float* x         = (const float*)d_in[0];
  const float* in_proj_w = (const float*)d_in[1];
  const float* conv_w    = (const float*)d_in[2];
  const float* conv_b    = (const float*)d_in[3];
  const float* x_proj_w  = (const float*)d_in[4];
  const float* dt_proj_w = (const float*)d_in[5];
  const float* dt_proj_b = (const float*)d_in[6];
  const float* A_log     = (const float*)d_in[7];
  const float* Dv        = (const float*)d_in[8];
  const float* out_proj_w= (const float*)d_in[9];
  float* out = (float*)d_out;

  float* ws    = (float*)d_ws;
  float* xz    = ws;                          // [2048][4096] f32
  float* xc    = xz    + (size_t)MM * 4096;   // [2048][2048] f32
  float* xdbl  = xc    + (size_t)MM * DINNER; // [2048][96]   f32
  float* delta = xdbl  + (size_t)MM * 96;     // [2048][2048] f32
  ushort* us   = (ushort*)(delta + (size_t)MM * DINNER);
  ushort* yhp  = us;                           // [2048][2048] bf16 hi
  ushort* ylp  = yhp + (size_t)MM * DINNER;    // repurposed: dt/wd planes
  ushort* xh   = ylp + (size_t)MM * DINNER;    // [2048][1024]
  ushort* xl   = xh  + (size_t)MM * DMODEL;
  ushort* wih  = xl  + (size_t)MM * DMODEL;    // [4096][1024]
  ushort* wil  = wih + (size_t)4096 * DMODEL;
  ushort* woh  = wil + (size_t)4096 * DMODEL;  // [1024][2048]
  ushort* wol  = woh + (size_t)DMODEL * DINNER;

  // dt hi/lo + dt_proj_w hi/lo live in the old yl region (never else used)
  ushort* dth = ylp;
  ushort* dtl = ylp + 131072;
  ushort* wdh = ylp + 262144;
  ushort* wdl = ylp + 393216;

  // hend/aprod/hin (scan) live in wih/wil (dead after in_proj GEMM)
  float* hend  = (float*)wih;
  float* aprod = hend  + (size_t)BB * NCH * DINNER * DSTATE;
  float* hin   = aprod + (size_t)BB * NCH * DINNER * DSTATE;
  // x_proj split-K partials [8][2048][96] = 6.3 MB (consumed before scan)
  float* part  = hend;
  // out_proj split-K partials [4][2048][1024] f32 = 33.55 MB: exactly the xz
  // region (dead after scan_apply reads the z half)
  float* opart = xz;

  const dim3 blk(256);

  // 0) fused precision splits (x, in_proj_w, out_proj_w, dt_proj_w)
  {
    const int n0 = (MM * DMODEL) / 4, n1 = (4096 * DMODEL) / 4,
              n2 = (DMODEL * DINNER) / 4, n3 = (DINNER * DTRANK) / 4;
    split3<<<dim3((n0 + n1 + n2 + n3) / 256), blk, 0, stream>>>(
        x, xh, xl, n0, in_proj_w, wih, wil, n1,
        out_proj_w, woh, wol, n2, dt_proj_w, wdh, wdl, n3);
  }

  // 1) in_proj (MFMA split-bf16 3-product): xz = x @ in_proj_w^T
  gemm_hl_mfma<0,1><<<dim3(4096 / 128, MM / 128), blk, 0, stream>>>(
      xh, xl, wih, wil, xz, nullptr, MM, 4096, DMODEL);

  // 2) causal depthwise conv + silu -> xc
  conv_silu<<<dim3((MM * DINNER / 4) / 256), blk, 0, stream>>>(xz, conv_w, conv_b, xc);

  // 3) x_proj split-K + fused reduce/dt-split
  gemm_nt_part<64,32,4,2,256><<<dim3(96/32, MM/64, 8), blk, 0, stream>>>(
      xc, x_proj_w, part, MM, 96, DINNER, DINNER);
  xpr_fused<<<dim3((MM * 24 + 255) / 256), blk, 0, stream>>>(part, xdbl, dth, dtl);

  // 4) dt_proj (MFMA split-bf16 + softplus)
  gemm_hl_mfma<1,1><<<dim3(DINNER / 128, MM / 128), blk, 0, stream>>>(
      dth, dtl, wdh, wdl, delta, dt_proj_b, MM, DINNER, DTRANK);

  // 5) chunked parallel scan
  scan_chunk_state<<<dim3(BB * 128 * NCH), dim3(64), 0, stream>>>(
      delta, xc, xdbl, A_log, hend, aprod);
  scan_combine<<<dim3(BB * DINNER * DSTATE / 256), blk, 0, stream>>>(
      hend, aprod, hin);
  scan_apply<<<dim3(BB * 128 * NCH), dim3(64), 0, stream>>>(
      delta, xc, xdbl, xz, A_log, Dv, hin, yhp);

  // 6) out_proj (2-product MFMA, split-K=4): out = y @ out_proj_w^T
  gemm_p2_mfma<4><<<dim3(DMODEL / 128, MM / 128, 4), blk, 0, stream>>>(
      yhp, woh, wol, opart, MM, DMODEL, DINNER);
  splitk_reduce4<<<dim3((MM * DMODEL) / 1024), blk, 0, stream>>>(
      opart, out, MM * DMODEL);
}

// Round 8
// 183.056 us; speedup vs baseline: 7.3607x; 1.0906x over previous
//
#include <hip/hip_runtime.h>
#include <math.h>
#include <stdint.h>

#define DMODEL 1024
#define DINNER 2048
#define DCONV  4
#define DSTATE 16
#define DTRANK 64
#define BB 2
#define LL 1024
#define MM (BB * LL)            // 2048 rows in all GEMMs

#define CL  64                  // scan chunk length
#define NCH (LL / CL)           // 16 chunks

#define AS1(p) ((__attribute__((address_space(1))) void*)(void*)(p))
#define AS3(p) ((__attribute__((address_space(3))) void*)(void*)(p))

typedef __attribute__((ext_vector_type(8))) short bf16x8;
typedef __attribute__((ext_vector_type(4))) float f32x4;

__device__ __forceinline__ ushort bf16_rne(float f) {
  uint32_t u = __float_as_uint(f);
  uint32_t r = (u + 0x7fffu + ((u >> 16) & 1u)) >> 16;
  return (ushort)r;
}

// ---------------------------------------------------------------------------
// Fused f32 -> (hi[, lo]) bf16 split for 4 arrays in one launch.
// lo == nullptr -> hi-only cast.
// ---------------------------------------------------------------------------
__device__ __forceinline__ void split4(const float* __restrict__ in,
                                       ushort* __restrict__ hi,
                                       ushort* __restrict__ lo, int i4) {
  const float4 v = *reinterpret_cast<const float4*>(in + (size_t)i4 * 4);
  ushort4 h;
  h.x = bf16_rne(v.x); h.y = bf16_rne(v.y);
  h.z = bf16_rne(v.z); h.w = bf16_rne(v.w);
  *reinterpret_cast<ushort4*>(hi + (size_t)i4 * 4) = h;
  if (lo) {
    ushort4 l;
    l.x = bf16_rne(v.x - __uint_as_float((uint)h.x << 16));
    l.y = bf16_rne(v.y - __uint_as_float((uint)h.y << 16));
    l.z = bf16_rne(v.z - __uint_as_float((uint)h.z << 16));
    l.w = bf16_rne(v.w - __uint_as_float((uint)h.w << 16));
    *reinterpret_cast<ushort4*>(lo + (size_t)i4 * 4) = l;
  }
}

__global__ __launch_bounds__(256)
void split3(const float* s0, ushort* h0, ushort* l0, int n0,
            const float* s1, ushort* h1, ushort* l1, int n1,
            const float* s2, ushort* h2, ushort* l2, int n2,
            const float* s3, ushort* h3, ushort* l3, int n3) {
  int i = blockIdx.x * 256 + threadIdx.x;
  if (i < n0) { split4(s0, h0, l0, i); return; }
  i -= n0;
  if (i < n1) { split4(s1, h1, l1, i); return; }
  i -= n1;
  if (i < n2) { split4(s2, h2, l2, i); return; }
  i -= n2;
  if (i < n3) { split4(s3, h3, l3, i); return; }
}

__device__ __forceinline__ int swz4(int r) { return (r & 3) ^ ((r >> 2) & 3); }

// ---------------------------------------------------------------------------
// Split-precision bf16 MFMA NT GEMM (3-product), 2-phase double-buffered.
// Used only for dt_proj (error-critical path through exp(delta*A)).
// EPI 1: C=softplus(acc+bias[n]).
// ---------------------------------------------------------------------------
template<int EPI, int SPLITK>
__global__ __launch_bounds__(256)
void gemm_hl_mfma(const ushort* __restrict__ Ahg, const ushort* __restrict__ Alg,
                  const ushort* __restrict__ Bhg, const ushort* __restrict__ Blg,
                  float* __restrict__ C, const float* __restrict__ bias,
                  int M, int N, int K) {
  __shared__ ushort Ah[2][128][32];
  __shared__ ushort Al[2][128][32];
  __shared__ ushort Bh[2][128][32];
  __shared__ ushort Bl[2][128][32];

  const int tid  = threadIdx.x;
  const int wave = tid >> 6;
  const int lane = tid & 63;
  const int m0 = blockIdx.y * 128;
  const int n0 = blockIdx.x * 128;
  const int wm = (wave >> 1) * 64;
  const int wn = (wave & 1) * 64;

  const int ksl = K / SPLITK;
  const int kb  = blockIdx.z * ksl;
  float* Cout   = C + (size_t)blockIdx.z * M * N;

  f32x4 acc[4][4];
  #pragma unroll
  for (int i = 0; i < 4; ++i)
    #pragma unroll
    for (int j = 0; j < 4; ++j)
      acc[i][j] = (f32x4){0.f, 0.f, 0.f, 0.f};

  const ushort* gsrc; ushort* dst; int row0;
  if      (wave == 0) { gsrc = Ahg; dst = &Ah[0][0][0]; row0 = m0; }
  else if (wave == 1) { gsrc = Alg; dst = &Al[0][0][0]; row0 = m0; }
  else if (wave == 2) { gsrc = Bhg; dst = &Bh[0][0][0]; row0 = n0; }
  else                { gsrc = Blg; dst = &Bl[0][0][0]; row0 = n0; }

  const int lr = lane >> 2;
  const int ls = lane & 3;
  const int fr = lane & 15;
  const int q  = lane >> 4;

  auto STAGE = [&](int bi, int k0) {
    ushort* d = dst + bi * 4096;
    #pragma unroll
    for (int seg = 0; seg < 8; ++seg) {
      const int rho = seg * 16 + lr;
      const int ks  = (ls ^ swz4(rho)) * 8;
      __builtin_amdgcn_global_load_lds(
          AS1(gsrc + (size_t)(row0 + rho) * K + k0 + ks),
          AS3(d + seg * 512), 16, 0, 0);
    }
  };

  const int NT = ksl / 32;
  STAGE(0, kb);
  __syncthreads();

  int cur = 0;
  for (int kt = 0; kt < NT; ++kt) {
    if (kt + 1 < NT) STAGE(cur ^ 1, kb + (kt + 1) * 32);

    bf16x8 ah[4], al[4], bh[4], bl[4];
    #pragma unroll
    for (int f = 0; f < 4; ++f) {
      { const int r = wm + f * 16 + fr; const int s = 8 * (q ^ swz4(r));
        ah[f] = *reinterpret_cast<const bf16x8*>(&Ah[cur][r][s]);
        al[f] = *reinterpret_cast<const bf16x8*>(&Al[cur][r][s]); }
      { const int r = wn + f * 16 + fr; const int s = 8 * (q ^ swz4(r));
        bh[f] = *reinterpret_cast<const bf16x8*>(&Bh[cur][r][s]);
        bl[f] = *reinterpret_cast<const bf16x8*>(&Bl[cur][r][s]); }
    }
    #pragma unroll
    for (int i = 0; i < 4; ++i)
      #pragma unroll
      for (int j = 0; j < 4; ++j) {
        acc[i][j] = __builtin_amdgcn_mfma_f32_16x16x32_bf16(ah[i], bh[j], acc[i][j], 0, 0, 0);
        acc[i][j] = __builtin_amdgcn_mfma_f32_16x16x32_bf16(al[i], bh[j], acc[i][j], 0, 0, 0);
        acc[i][j] = __builtin_amdgcn_mfma_f32_16x16x32_bf16(ah[i], bl[j], acc[i][j], 0, 0, 0);
      }

    __syncthreads();
    cur ^= 1;
  }

  const int cr = (lane >> 4) * 4;
  const int cc = lane & 15;
  #pragma unroll
  for (int i = 0; i < 4; ++i)
    #pragma unroll
    for (int j = 0; j < 4; ++j) {
      const int cn = n0 + wn + j * 16 + cc;
      const float bj = (EPI == 1) ? bias[cn] : 0.f;
      const size_t base = (size_t)(m0 + wm + i * 16 + cr) * N + cn;
      #pragma unroll
      for (int r = 0; r < 4; ++r) {
        float v = acc[i][j][r];
        if (EPI == 1) {
          v += bj;
          v = fmaxf(v, 0.f) + __logf(1.f + __expf(-fabsf(v)));   // softplus
        }
        Cout[base + (size_t)r * N] = v;
      }
    }
}

// ---------------------------------------------------------------------------
// 2-product MFMA NT GEMM: C = Ah @ (Bh+Bl)^T, 3 staged planes, 48 KB LDS.
// EPI 0: plain.  EPI 2: silu for columns cn >= 2048 (in_proj z-gate fusion).
// SPLITK via blockIdx.z.
// ---------------------------------------------------------------------------
template<int EPI, int SPLITK>
__global__ __launch_bounds__(256)
void gemm_p2_mfma(const ushort* __restrict__ Ahg, const ushort* __restrict__ Bhg,
                  const ushort* __restrict__ Blg, float* __restrict__ P,
                  int M, int N, int K) {
  __shared__ ushort Ah[2][128][32];
  __shared__ ushort Bh[2][128][32];
  __shared__ ushort Bl[2][128][32];

  const int tid  = threadIdx.x;
  const int wave = tid >> 6;
  const int lane = tid & 63;
  const int m0 = blockIdx.y * 128;
  const int n0 = blockIdx.x * 128;
  const int wm = (wave >> 1) * 64;
  const int wn = (wave & 1) * 64;

  const int ksl = K / SPLITK;
  const int kb  = blockIdx.z * ksl;
  float* Cout   = P + (size_t)blockIdx.z * M * N;

  f32x4 acc[4][4];
  #pragma unroll
  for (int i = 0; i < 4; ++i)
    #pragma unroll
    for (int j = 0; j < 4; ++j)
      acc[i][j] = (f32x4){0.f, 0.f, 0.f, 0.f};

  const ushort* gsrc = nullptr; ushort* dst = nullptr; int row0 = 0;
  if      (wave == 0) { gsrc = Ahg; dst = &Ah[0][0][0]; row0 = m0; }
  else if (wave == 1) { gsrc = Bhg; dst = &Bh[0][0][0]; row0 = n0; }
  else if (wave == 2) { gsrc = Blg; dst = &Bl[0][0][0]; row0 = n0; }

  const int lr = lane >> 2;
  const int ls = lane & 3;
  const int fr = lane & 15;
  const int q  = lane >> 4;

  auto STAGE = [&](int bi, int k0) {
    if (wave >= 3) return;
    ushort* d = dst + bi * 4096;
    #pragma unroll
    for (int seg = 0; seg < 8; ++seg) {
      const int rho = seg * 16 + lr;
      const int ks  = (ls ^ swz4(rho)) * 8;
      __builtin_amdgcn_global_load_lds(
          AS1(gsrc + (size_t)(row0 + rho) * K + k0 + ks),
          AS3(d + seg * 512), 16, 0, 0);
    }
  };

  const int NT = ksl / 32;
  STAGE(0, kb);
  __syncthreads();

  int cur = 0;
  for (int kt = 0; kt < NT; ++kt) {
    if (kt + 1 < NT) STAGE(cur ^ 1, kb + (kt + 1) * 32);

    bf16x8 ah[4], bh[4], bl[4];
    #pragma unroll
    for (int f = 0; f < 4; ++f) {
      { const int r = wm + f * 16 + fr; const int s = 8 * (q ^ swz4(r));
        ah[f] = *reinterpret_cast<const bf16x8*>(&Ah[cur][r][s]); }
      { const int r = wn + f * 16 + fr; const int s = 8 * (q ^ swz4(r));
        bh[f] = *reinterpret_cast<const bf16x8*>(&Bh[cur][r][s]);
        bl[f] = *reinterpret_cast<const bf16x8*>(&Bl[cur][r][s]); }
    }
    #pragma unroll
    for (int i = 0; i < 4; ++i)
      #pragma unroll
      for (int j = 0; j < 4; ++j) {
        acc[i][j] = __builtin_amdgcn_mfma_f32_16x16x32_bf16(ah[i], bh[j], acc[i][j], 0, 0, 0);
        acc[i][j] = __builtin_amdgcn_mfma_f32_16x16x32_bf16(ah[i], bl[j], acc[i][j], 0, 0, 0);
      }

    __syncthreads();
    cur ^= 1;
  }

  const int cr = (lane >> 4) * 4;
  const int cc = lane & 15;
  #pragma unroll
  for (int i = 0; i < 4; ++i)
    #pragma unroll
    for (int j = 0; j < 4; ++j) {
      const int cn = n0 + wn + j * 16 + cc;
      const size_t base = (size_t)(m0 + wm + i * 16 + cr) * N + cn;
      #pragma unroll
      for (int r = 0; r < 4; ++r) {
        float v = acc[i][j][r];
        if (EPI == 2 && cn >= DINNER)
          v = v / (1.f + __expf(-v));     // silu: z-gate precompute
        Cout[base + (size_t)r * N] = v;
      }
    }
}

// sum 4 split-K partial planes -> out
__global__ __launch_bounds__(256)
void splitk_reduce4(const float* __restrict__ P, float* __restrict__ out, int n) {
  const int i = (blockIdx.x * 256 + threadIdx.x) * 4;
  if (i >= n) return;
  float4 s = *reinterpret_cast<const float4*>(P + i);
  #pragma unroll
  for (int z = 1; z < 4; ++z) {
    const float4 v = *reinterpret_cast<const float4*>(P + (size_t)z * n + i);
    s.x += v.x; s.y += v.y; s.z += v.z; s.w += v.w;
  }
  *reinterpret_cast<float4*>(out + i) = s;
}

// ---------------------------------------------------------------------------
// Split-K f32 NT GEMM partials (x_proj)
// ---------------------------------------------------------------------------
template<int BM, int BN, int TM, int TN, int KSLICE>
__global__ __launch_bounds__(256)
void gemm_nt_part(const float* __restrict__ A, const float* __restrict__ Bw,
                  float* __restrict__ P, int M, int N, int lda, int ldb) {
  constexpr int BK  = 16;
  constexpr int NTX = BN / TN;
  constexpr int NTY = BM / TM;
  static_assert(NTX * NTY == 256, "thread tile mismatch");
  __shared__ float As[BK][BM + 4];
  __shared__ float Bs[BK][BN + 4];

  const int tid = threadIdx.x;
  const int m0  = blockIdx.y * BM;
  const int n0  = blockIdx.x * BN;
  const int kb  = blockIdx.z * KSLICE;
  const int tx  = tid % NTX;
  const int ty  = tid / NTX;

  float acc[TM][TN] = {};

  for (int k0 = kb; k0 < kb + KSLICE; k0 += BK) {
    __syncthreads();
    for (int t = tid; t < BM * 4; t += 256) {
      const int row = t >> 2, kq = t & 3;
      const float4 v = *reinterpret_cast<const float4*>(
          A + (size_t)(m0 + row) * lda + k0 + kq * 4);
      As[kq * 4 + 0][row] = v.x;
      As[kq * 4 + 1][row] = v.y;
      As[kq * 4 + 2][row] = v.z;
      As[kq * 4 + 3][row] = v.w;
    }
    for (int t = tid; t < BN * 4; t += 256) {
      const int row = t >> 2, kq = t & 3;
      const float4 v = *reinterpret_cast<const float4*>(
          Bw + (size_t)(n0 + row) * ldb + k0 + kq * 4);
      Bs[kq * 4 + 0][row] = v.x;
      Bs[kq * 4 + 1][row] = v.y;
      Bs[kq * 4 + 2][row] = v.z;
      Bs[kq * 4 + 3][row] = v.w;
    }
    __syncthreads();
    #pragma unroll
    for (int k = 0; k < BK; ++k) {
      float a[TM], b[TN];
      #pragma unroll
      for (int i = 0; i < TM; ++i) a[i] = As[k][ty * TM + i];
      #pragma unroll
      for (int j = 0; j < TN; ++j) b[j] = Bs[k][tx * TN + j];
      #pragma unroll
      for (int i = 0; i < TM; ++i)
        #pragma unroll
        for (int j = 0; j < TN; ++j)
          acc[i][j] = fmaf(a[i], b[j], acc[i][j]);
    }
  }

  float* out = P + (size_t)blockIdx.z * M * N;
  #pragma unroll
  for (int i = 0; i < TM; ++i)
    #pragma unroll
    for (int j = 0; j < TN; ++j)
      out[(size_t)(m0 + ty * TM + i) * N + n0 + tx * TN + j] = acc[i][j];
}

// reduce x_proj partials; dt cols (0..63) -> packed bf16 hi/lo, B/C cols -> f32
__global__ __launch_bounds__(256)
void xpr_fused(const float* __restrict__ part, float* __restrict__ xdbl,
               ushort* __restrict__ dth, ushort* __restrict__ dtl) {
  const int i = blockIdx.x * 256 + threadIdx.x;   // float4 over [2048][24]
  if (i >= MM * 24) return;
  const int m  = i / 24;
  const int c4 = (i % 24) * 4;
  const size_t off = (size_t)m * 96 + c4;
  float4 s = *reinterpret_cast<const float4*>(part + off);
  #pragma unroll
  for (int z = 1; z < 8; ++z) {
    const float4 v = *reinterpret_cast<const float4*>(part + (size_t)z * MM * 96 + off);
    s.x += v.x; s.y += v.y; s.z += v.z; s.w += v.w;
  }
  if (c4 < 64) {
    ushort4 h, l;
    h.x = bf16_rne(s.x); l.x = bf16_rne(s.x - __uint_as_float((uint)h.x << 16));
    h.y = bf16_rne(s.y); l.y = bf16_rne(s.y - __uint_as_float((uint)h.y << 16));
    h.z = bf16_rne(s.z); l.z = bf16_rne(s.z - __uint_as_float((uint)h.z << 16));
    h.w = bf16_rne(s.w); l.w = bf16_rne(s.w - __uint_as_float((uint)h.w << 16));
    *reinterpret_cast<ushort4*>(dth + (size_t)m * 64 + c4) = h;
    *reinterpret_cast<ushort4*>(dtl + (size_t)m * 64 + c4) = l;
  } else {
    *reinterpret_cast<float4*>(xdbl + off) = s;
  }
}

// ---------------------------------------------------------------------------
// Depthwise causal conv1d (k=4) + bias + SiLU, float4-vectorized.
// ---------------------------------------------------------------------------
__global__ __launch_bounds__(256)
void conv_silu(const float* __restrict__ xz, const float* __restrict__ cw,
               const float* __restrict__ cb, float* __restrict__ xc) {
  const int idx = blockIdx.x * 256 + threadIdx.x;   // over MM*DINNER/4
  if (idx >= MM * DINNER / 4) return;
  const int d4 = (idx & 511) * 4;       // DINNER/4 = 512 per row
  const int m  = idx >> 9;
  const int l  = m & (LL - 1);
  const int b  = m >> 10;

  float4 w0 = *reinterpret_cast<const float4*>(cw + (size_t)(d4 + 0) * 4);
  float4 w1 = *reinterpret_cast<const float4*>(cw + (size_t)(d4 + 1) * 4);
  float4 w2 = *reinterpret_cast<const float4*>(cw + (size_t)(d4 + 2) * 4);
  float4 w3 = *reinterpret_cast<const float4*>(cw + (size_t)(d4 + 3) * 4);
  float4 acc = *reinterpret_cast<const float4*>(cb + d4);

  #pragma unroll
  for (int j = 0; j < DCONV; ++j) {
    const int ll = l - (DCONV - 1) + j;
    if (ll >= 0) {
      const float4 xv = *reinterpret_cast<const float4*>(
          xz + ((size_t)(b * LL + ll) << 12) + d4);
      acc.x = fmaf(xv.x, (&w0.x)[j], acc.x);
      acc.y = fmaf(xv.y, (&w1.x)[j], acc.y);
      acc.z = fmaf(xv.z, (&w2.x)[j], acc.z);
      acc.w = fmaf(xv.w, (&w3.x)[j], acc.w);
    }
  }
  float4 o;
  o.x = acc.x / (1.f + __expf(-acc.x));
  o.y = acc.y / (1.f + __expf(-acc.y));
  o.z = acc.z / (1.f + __expf(-acc.z));
  o.w = acc.w / (1.f + __expf(-acc.w));
  *reinterpret_cast<float4*>(xc + (size_t)m * DINNER + d4) = o;
}

// ---------------------------------------------------------------------------
// Chunked parallel selective scan (3 passes).
// ---------------------------------------------------------------------------
__device__ __forceinline__ void stage_tile(const float* g, int stride,
                                           float* ldst, int lane) {
  const int r  = lane >> 2;
  const int q4 = (lane & 3) * 4;
  #pragma unroll
  for (int i = 0; i < 4; ++i) {
    __builtin_amdgcn_global_load_lds(
        AS1(g + (size_t)(i * 16 + r) * stride + q4),
        AS3(ldst + i * 256), 16, 0, 0);
  }
}

__device__ __forceinline__ float quad_sum(float v) {
  int i = __float_as_int(v);
  v += __int_as_float(__builtin_amdgcn_update_dpp(0, i, 0xB1, 0xf, 0xf, true)); // xor 1
  i = __float_as_int(v);
  v += __int_as_float(__builtin_amdgcn_update_dpp(0, i, 0x4E, 0xf, 0xf, true)); // xor 2
  return v;
}

__global__ __launch_bounds__(64)
void scan_chunk_state(const float* __restrict__ delta, const float* __restrict__ xc,
                      const float* __restrict__ xdbl, const float* __restrict__ A_log,
                      float* __restrict__ hend, float* __restrict__ aprod) {
  __shared__ float dT[CL][16];
  __shared__ float xT[CL][16];
  __shared__ float bT[CL][16];

  const int idx = blockIdx.x;          // (b*128 + dg)*16 + c
  const int c  = idx & 15;
  const int dg = (idx >> 4) & 127;
  const int b  = idx >> 11;
  const int t  = threadIdx.x;
  const int ch = t >> 2;
  const int q  = t & 3;
  const int d  = dg * 16 + ch;

  const size_t r0 = (size_t)b * LL + (size_t)c * CL;
  stage_tile(delta + r0 * DINNER + dg * 16, DINNER, &dT[0][0], t);
  stage_tile(xc    + r0 * DINNER + dg * 16, DINNER, &xT[0][0], t);
  stage_tile(xdbl  + r0 * 96 + DTRANK,          96, &bT[0][0], t);

  float Adn[4];
  #pragma unroll
  for (int j = 0; j < 4; ++j)
    Adn[j] = -__expf(A_log[d * DSTATE + 4 * q + j]);
  float h0 = 0.f, h1 = 0.f, h2 = 0.f, h3 = 0.f;
  float p0 = 1.f, p1 = 1.f, p2 = 1.f, p3 = 1.f;

  __syncthreads();

  #pragma unroll 8
  for (int l = 0; l < CL; ++l) {
    const float dv = dT[l][ch];
    const float xv = xT[l][ch];
    const float4 B4 = *reinterpret_cast<const float4*>(&bT[l][4 * q]);
    const float dvx = dv * xv;
    const float a0 = __expf(dv * Adn[0]);
    const float a1 = __expf(dv * Adn[1]);
    const float a2 = __expf(dv * Adn[2]);
    const float a3 = __expf(dv * Adn[3]);
    h0 = fmaf(a0, h0, dvx * B4.x);  p0 *= a0;
    h1 = fmaf(a1, h1, dvx * B4.y);  p1 *= a1;
    h2 = fmaf(a2, h2, dvx * B4.z);  p2 *= a2;
    h3 = fmaf(a3, h3, dvx * B4.w);  p3 *= a3;
  }

  const size_t base = (((size_t)(b * NCH + c) * DINNER) + d) * DSTATE + 4 * q;
  *reinterpret_cast<float4*>(hend  + base) = (float4){h0, h1, h2, h3};
  *reinterpret_cast<float4*>(aprod + base) = (float4){p0, p1, p2, p3};
}

__global__ __launch_bounds__(256)
void scan_combine(const float* __restrict__ hend, const float* __restrict__ aprod,
                  float* __restrict__ hin) {
  const int tid = blockIdx.x * 256 + threadIdx.x;   // 65536 total
  const size_t cstride = (size_t)DINNER * DSTATE;   // 32768
  const size_t base = (size_t)(tid >> 15) * NCH * cstride + (tid & 32767);
  float h = 0.f;
  hin[base] = 0.f;
  #pragma unroll
  for (int c = 0; c < NCH - 1; ++c) {
    h = fmaf(aprod[base + (size_t)c * cstride], h, hend[base + (size_t)c * cstride]);
    hin[base + (size_t)(c + 1) * cstride] = h;
  }
}

__global__ __launch_bounds__(64)
void scan_apply(const float* __restrict__ delta, const float* __restrict__ xc,
                const float* __restrict__ xdbl, const float* __restrict__ xz,
                const float* __restrict__ A_log, const float* __restrict__ Dp,
                const float* __restrict__ hin, ushort* __restrict__ yh) {
  __shared__ float dT[CL][16];
  __shared__ float xT[CL][16];
  __shared__ float bT[CL][16];
  __shared__ float cT[CL][16];
  __shared__ float zT[CL][16];

  const int idx = blockIdx.x;
  const int c  = idx & 15;
  const int dg = (idx >> 4) & 127;
  const int b  = idx >> 11;
  const int t  = threadIdx.x;
  const int ch = t >> 2;
  const int q  = t & 3;
  const int d  = dg * 16 + ch;

  const size_t r0 = (size_t)b * LL + (size_t)c * CL;
  stage_tile(delta + r0 * DINNER + dg * 16, DINNER, &dT[0][0], t);
  stage_tile(xc    + r0 * DINNER + dg * 16, DINNER, &xT[0][0], t);
  stage_tile(xdbl  + r0 * 96 + DTRANK,          96, &bT[0][0], t);
  stage_tile(xdbl  + r0 * 96 + DTRANK + DSTATE, 96, &cT[0][0], t);
  stage_tile(xz    + (r0 << 12) + DINNER + dg * 16, 4096, &zT[0][0], t);

  float Adn[4];
  #pragma unroll
  for (int j = 0; j < 4; ++j)
    Adn[j] = -__expf(A_log[d * DSTATE + 4 * q + j]);
  const float Dd = Dp[d];

  const size_t base = (((size_t)(b * NCH + c) * DINNER) + d) * DSTATE + 4 * q;
  const float4 h4 = *reinterpret_cast<const float4*>(hin + base);
  float h0 = h4.x, h1 = h4.y, h2 = h4.z, h3 = h4.w;

  __syncthreads();

  #pragma unroll 8
  for (int l = 0; l < CL; ++l) {
    const float dv = dT[l][ch];
    const float xv = xT[l][ch];
    const float4 B4 = *reinterpret_cast<const float4*>(&bT[l][4 * q]);
    const float4 C4 = *reinterpret_cast<const float4*>(&cT[l][4 * q]);
    const float dvx = dv * xv;
    const float a0 = __expf(dv * Adn[0]);
    const float a1 = __expf(dv * Adn[1]);
    const float a2 = __expf(dv * Adn[2]);
    const float a3 = __expf(dv * Adn[3]);
    h0 = fmaf(a0, h0, dvx * B4.x);
    h1 = fmaf(a1, h1, dvx * B4.y);
    h2 = fmaf(a2, h2, dvx * B4.z);
    h3 = fmaf(a3, h3, dvx * B4.w);
    float ys = fmaf(h0, C4.x, fmaf(h1, C4.y, fmaf(h2, C4.z, h3 * C4.w)));
    ys = quad_sum(ys);
    if (q == 0) {
      const float g = zT[l][ch];        // silu(z) precomputed by in_proj epilogue
      const float tv = (ys + xv * Dd) * g;
      yh[(r0 + l) * (size_t)DINNER + d] = bf16_rne(tv);
    }
  }
}

// ---------------------------------------------------------------------------
extern "C" void kernel_launch(void* const* d_in, const int* in_sizes, int n_in,
                              void* d_out, int out_size, void* d_ws, size_t ws_size,
                              hipStream_t stream) {
  const float* x         = (const float*)d_in[0];
  const float* in_proj_w = (const float*)d_in[1];
  const float* conv_w    = (const float*)d_in[2];
  const float* conv_b    = (const float*)d_in[3];
  const float* x_proj_w  = (const float*)d_in[4];
  const float* dt_proj_w = (const float*)d_in[5];
  const float* dt_proj_b = (const float*)d_in[6];
  const float* A_log     = (const float*)d_in[7];
  const float* Dv        = (const float*)d_in[8];
  const float* out_proj_w= (const float*)d_in[9];
  float* out = (float*)d_out;

  float* ws    = (float*)d_ws;
  float* xz    = ws;                          // [2048][4096] f32
  float* xc    = xz    + (size_t)MM * 4096;   // [2048][2048] f32
  float* xdbl  = xc    + (size_t)MM * DINNER; // [2048][96]   f32
  float* delta = xdbl  + (size_t)MM * 96;     // [2048][2048] f32
  ushort* us   = (ushort*)(delta + (size_t)MM * DINNER);
  ushort* yhp  = us;                           // [2048][2048] bf16 hi
  ushort* ylp  = yhp + (size_t)MM * DINNER;    // repurposed: dt/wd planes
  ushort* xh   = ylp + (size_t)MM * DINNER;    // [2048][1024]
  ushort* xl   = xh  + (size_t)MM * DMODEL;    // (unused)
  ushort* wih  = xl  + (size_t)MM * DMODEL;    // [4096][1024]
  ushort* wil  = wih + (size_t)4096 * DMODEL;
  ushort* woh  = wil + (size_t)4096 * DMODEL;  // [1024][2048]
  ushort* wol  = woh + (size_t)DMODEL * DINNER;

  // dt hi/lo + dt_proj_w hi/lo live in the old yl region (never else used)
  ushort* dth = ylp;
  ushort* dtl = ylp + 131072;
  ushort* wdh = ylp + 262144;
  ushort* wdl = ylp + 393216;

  // hend/aprod/hin (scan) live in wih/wil (dead after in_proj GEMM)
  float* hend  = (float*)wih;
  float* aprod = hend  + (size_t)BB * NCH * DINNER * DSTATE;
  float* hin   = aprod + (size_t)BB * NCH * DINNER * DSTATE;
  // x_proj split-K partials [8][2048][96] = 6.3 MB (consumed before scan)
  float* part  = hend;
  // out_proj split-K partials [4][2048][1024] f32 = 33.55 MB: the xz region
  // (dead after scan_apply reads the z half)
  float* opart = xz;

  const dim3 blk(256);

  // 0) fused precision splits (x hi-only, in_proj_w, out_proj_w, dt_proj_w)
  {
    const int n0 = (MM * DMODEL) / 4, n1 = (4096 * DMODEL) / 4,
              n2 = (DMODEL * DINNER) / 4, n3 = (DINNER * DTRANK) / 4;
    split3<<<dim3((n0 + n1 + n2 + n3) / 256), blk, 0, stream>>>(
        x, xh, nullptr, n0, in_proj_w, wih, wil, n1,
        out_proj_w, woh, wol, n2, dt_proj_w, wdh, wdl, n3);
  }

  // 1) in_proj (2-product MFMA + fused z-gate silu): xz = x @ in_proj_w^T,
  //    columns >= 2048 stored as silu(z).
  gemm_p2_mfma<2,1><<<dim3(4096 / 128, MM / 128), blk, 0, stream>>>(
      xh, wih, wil, xz, MM, 4096, DMODEL);

  // 2) causal depthwise conv + silu -> xc
  conv_silu<<<dim3((MM * DINNER / 4) / 256), blk, 0, stream>>>(xz, conv_w, conv_b, xc);

  // 3) x_proj split-K + fused reduce/dt-split
  gemm_nt_part<64,32,4,2,256><<<dim3(96/32, MM/64, 8), blk, 0, stream>>>(
      xc, x_proj_w, part, MM, 96, DINNER, DINNER);
  xpr_fused<<<dim3((MM * 24 + 255) / 256), blk, 0, stream>>>(part, xdbl, dth, dtl);

  // 4) dt_proj (MFMA split-bf16 3-product + softplus)
  gemm_hl_mfma<1,1><<<dim3(DINNER / 128, MM / 128), blk, 0, stream>>>(
      dth, dtl, wdh, wdl, delta, dt_proj_b, MM, DINNER, DTRANK);

  // 5) chunked parallel scan
  scan_chunk_state<<<dim3(BB * 128 * NCH), dim3(64), 0, stream>>>(
      delta, xc, xdbl, A_log, hend, aprod);
  scan_combine<<<dim3(BB * DINNER * DSTATE / 256), blk, 0, stream>>>(
      hend, aprod, hin);
  scan_apply<<<dim3(BB * 128 * NCH), dim3(64), 0, stream>>>(
      delta, xc, xdbl, xz, A_log, Dv, hin, yhp);

  // 6) out_proj (2-product MFMA, split-K=4): out = y @ out_proj_w^T
  gemm_p2_mfma<0,4><<<dim3(DMODEL / 128, MM / 128, 4), blk, 0, stream>>>(
      yhp, woh, wol, opart, MM, DMODEL, DINNER);
  splitk_reduce4<<<dim3((MM * DMODEL) / 1024), blk, 0, stream>>>(
      opart, out, MM * DMODEL);
}